// Round 1
// baseline (1376.919 us; speedup 1.0000x reference)
//
#include <hip/hip_runtime.h>

// Problem constants (from reference)
constexpr int B_ = 8, N_ = 10000, D_ = 128, H_ = 4, K_ = 256, DH_ = 32, M_ = 5000, DFF_ = 512;

__device__ __forceinline__ float bf2f(unsigned short u) {
    unsigned x = ((unsigned)u) << 16; float f; __builtin_memcpy(&f, &x, 4); return f;
}
__device__ __forceinline__ unsigned short f2bf(float f) {
    unsigned x; __builtin_memcpy(&x, &f, 4);
    x = (x + 0x7fffu + ((x >> 16) & 1u)) >> 16;   // RNE
    return (unsigned short)x;
}
__device__ __forceinline__ float gelu_exact(float v) {
    return 0.5f * v * (1.0f + erff(v * 0.70710678118654752f));
}

// ---------------------------------------------------------------------------
// Kernel 1: xe = x*emb_w + emb_b + PE(n,d);  hn = LN(xe; ln1)
// one wave per row; lane handles d = 2*lane, 2*lane+1 (lane == PE freq index j)
// ---------------------------------------------------------------------------
__global__ __launch_bounds__(256) void embed_ln_k(
    const float* __restrict__ x, const float* __restrict__ ew, const float* __restrict__ eb,
    const float* __restrict__ g, const float* __restrict__ bb,
    float* __restrict__ xe, float* __restrict__ hn)
{
    const int r = blockIdx.x * 4 + (threadIdx.x >> 6);   // r = b*N + n
    const int lane = threadIdx.x & 63;
    const int n = r % N_;
    const float xv = x[r];
    // div[j] = exp(2j * (-ln(10000)/128)); j = lane (D/2 == 64 == wave width)
    const float ang = (float)n * expf((float)lane * -0.14391156829962788f);
    float sv, cv; sincosf(ang, &sv, &cv);
    const int d0 = 2 * lane;
    float e0 = xv * ew[d0]     + eb[d0]     + sv;
    float e1 = xv * ew[d0 + 1] + eb[d0 + 1] + cv;
    float sum = e0 + e1, sq = e0 * e0 + e1 * e1;
    #pragma unroll
    for (int off = 32; off; off >>= 1) { sum += __shfl_xor(sum, off); sq += __shfl_xor(sq, off); }
    const float mu = sum * (1.f / 128.f);
    const float var = sq * (1.f / 128.f) - mu * mu;
    const float rs = rsqrtf(var + 1e-5f);
    const size_t base = (size_t)r * D_ + d0;
    float2 ev; ev.x = e0; ev.y = e1;
    *(float2*)&xe[base] = ev;
    float2 hv; hv.x = (e0 - mu) * rs * g[d0] + bb[d0]; hv.y = (e1 - mu) * rs * g[d0 + 1] + bb[d0 + 1];
    *(float2*)&hn[base] = hv;
}

// ---------------------------------------------------------------------------
// Generic LN over D=128 (row per wave)
// ---------------------------------------------------------------------------
__global__ __launch_bounds__(256) void ln_k(
    const float* __restrict__ in, const float* __restrict__ g, const float* __restrict__ bb,
    float* __restrict__ out)
{
    const int r = blockIdx.x * 4 + (threadIdx.x >> 6);
    const int lane = threadIdx.x & 63;
    const int d0 = 2 * lane;
    const size_t base = (size_t)r * D_ + d0;
    const float2 ev = *(const float2*)&in[base];
    float sum = ev.x + ev.y, sq = ev.x * ev.x + ev.y * ev.y;
    #pragma unroll
    for (int off = 32; off; off >>= 1) { sum += __shfl_xor(sum, off); sq += __shfl_xor(sq, off); }
    const float mu = sum * (1.f / 128.f);
    const float var = sq * (1.f / 128.f) - mu * mu;
    const float rs = rsqrtf(var + 1e-5f);
    float2 hv; hv.x = (ev.x - mu) * rs * g[d0] + bb[d0]; hv.y = (ev.y - mu) * rs * g[d0 + 1] + bb[d0 + 1];
    *(float2*)&out[base] = hv;
}

// ---------------------------------------------------------------------------
// Generic row GEMM: C[r,c] = sum_e A[r,e] * W[c,e]  (+bias)(+gelu)(+residual)
// block tile: 64 rows x 128 cols; per-thread 4r x 8c; e staged in chunks of 32
// transposed LDS ([e][r] / [e][c]) so per-thread reads are contiguous b128.
// ---------------------------------------------------------------------------
template<bool ABF16, bool GELU, bool RES, bool BIAS, bool CBF16>
__global__ __launch_bounds__(256) void gemm_k(
    const void* __restrict__ Av, const float* __restrict__ W, const float* __restrict__ bias,
    void* __restrict__ Cv, int CC, int EE)
{
    __shared__ float a_t[32][68];    // [e][r], padded
    __shared__ float w_t[32][132];   // [e][c], padded
    const int t = threadIdx.x;
    const int r0 = blockIdx.x * 64;
    const int c0 = blockIdx.y * 128;
    const int r4 = 4 * (t >> 4), c8 = 8 * (t & 15);
    float acc[4][8] = {};
    const float* Af = (const float*)Av;
    const unsigned short* Ab = (const unsigned short*)Av;

    for (int e0 = 0; e0 < EE; e0 += 32) {
        __syncthreads();
        #pragma unroll
        for (int i = 0; i < 8; ++i) {          // A tile 64x32
            int idx = t + i * 256; int e = idx & 31, r = idx >> 5;
            size_t gi = (size_t)(r0 + r) * EE + e0 + e;
            a_t[e][r] = ABF16 ? bf2f(Ab[gi]) : Af[gi];
        }
        #pragma unroll
        for (int i = 0; i < 16; ++i) {         // W tile 128x32
            int idx = t + i * 256; int e = idx & 31, c = idx >> 5;
            w_t[e][c] = W[(size_t)(c0 + c) * EE + e0 + e];
        }
        __syncthreads();
        #pragma unroll
        for (int e = 0; e < 32; ++e) {
            float a_[4], w_[8];
            *(float4*)a_       = *(const float4*)&a_t[e][r4];
            *(float4*)w_       = *(const float4*)&w_t[e][c8];
            *(float4*)(w_ + 4) = *(const float4*)&w_t[e][c8 + 4];
            #pragma unroll
            for (int i = 0; i < 4; ++i)
                #pragma unroll
                for (int j = 0; j < 8; ++j)
                    acc[i][j] = fmaf(a_[i], w_[j], acc[i][j]);
        }
    }

    #pragma unroll
    for (int i = 0; i < 4; ++i) {
        const size_t row = (size_t)(r0 + r4 + i);
        const size_t base = row * CC + c0 + c8;
        float v[8];
        #pragma unroll
        for (int j = 0; j < 8; ++j) {
            v[j] = acc[i][j];
            if (BIAS) v[j] += bias[c0 + c8 + j];
            if (GELU) v[j] = gelu_exact(v[j]);
            if (RES)  v[j] += ((const float*)Cv)[base + j];
        }
        if (CBF16) {
            unsigned short u[8];
            #pragma unroll
            for (int j = 0; j < 8; ++j) u[j] = f2bf(v[j]);
            uint4 pk;
            pk.x = (unsigned)u[0] | ((unsigned)u[1] << 16);
            pk.y = (unsigned)u[2] | ((unsigned)u[3] << 16);
            pk.z = (unsigned)u[4] | ((unsigned)u[5] << 16);
            pk.w = (unsigned)u[6] | ((unsigned)u[7] << 16);
            *(uint4*)((unsigned short*)Cv + base) = pk;
        } else {
            float4 s0, s1;
            s0.x = v[0]; s0.y = v[1]; s0.z = v[2]; s0.w = v[3];
            s1.x = v[4]; s1.y = v[5]; s1.z = v[6]; s1.w = v[7];
            *(float4*)&((float*)Cv)[base]     = s0;
            *(float4*)&((float*)Cv)[base + 4] = s1;
        }
    }
}

// ---------------------------------------------------------------------------
// Low-rank projection: out[b,k,e] += sum_n P[n,k] * hn[b,n,e]   (atomic over
// n-chunks). grid: x = 20 chunks of 512 n, y = ktile(4) * which(2), z = b.
// per-thread 4k x 8e; contraction nn scalar with contiguous b128 reads.
// ---------------------------------------------------------------------------
__global__ __launch_bounds__(256) void proj_kernel(
    const float* __restrict__ hn, const float* __restrict__ pK, const float* __restrict__ pV,
    float* __restrict__ oK, float* __restrict__ oV)
{
    __shared__ float p_lds[32][64];    // [nn][k]
    __shared__ float h_lds[32][128];   // [nn][e]
    const int t = threadIdx.x;
    const int k0 = (blockIdx.y & 3) * 64;
    const int which = blockIdx.y >> 2;
    const int b = blockIdx.z;
    const float* P = which ? pV : pK;
    float* out = which ? oV : oK;
    const int k4 = 4 * (t & 15), e8 = 8 * (t >> 4);
    float acc[4][8] = {};

    for (int s = 0; s < 16; ++s) {
        const int n0 = blockIdx.x * 512 + s * 32;
        __syncthreads();
        #pragma unroll
        for (int i = 0; i < 8; ++i) {
            int idx = t + i * 256; int j = idx & 63, nn = idx >> 6; int n = n0 + nn;
            p_lds[nn][j] = (n < N_) ? P[(size_t)n * K_ + k0 + j] : 0.f;
        }
        #pragma unroll
        for (int i = 0; i < 16; ++i) {
            int idx = t + i * 256; int e = idx & 127, nn = idx >> 7; int n = n0 + nn;
            h_lds[nn][e] = (n < N_) ? hn[((size_t)b * N_ + n) * D_ + e] : 0.f;
        }
        __syncthreads();
        #pragma unroll 4
        for (int nn = 0; nn < 32; ++nn) {
            float p_[4], h_[8];
            *(float4*)p_       = *(const float4*)&p_lds[nn][k4];
            *(float4*)h_       = *(const float4*)&h_lds[nn][e8];
            *(float4*)(h_ + 4) = *(const float4*)&h_lds[nn][e8 + 4];
            #pragma unroll
            for (int kk = 0; kk < 4; ++kk)
                #pragma unroll
                for (int ee = 0; ee < 8; ++ee)
                    acc[kk][ee] = fmaf(p_[kk], h_[ee], acc[kk][ee]);
        }
    }
    #pragma unroll
    for (int kk = 0; kk < 4; ++kk)
        #pragma unroll
        for (int ee = 0; ee < 8; ++ee)
            atomicAdd(&out[((size_t)b * K_ + k0 + k4 + kk) * D_ + e8 + ee], acc[kk][ee]);
}

// ---------------------------------------------------------------------------
// Attention: per (b,h), K/V slices [256][32] staged in LDS; each thread runs
// online softmax for 2 query rows.  out[b,n,h*32+dh] = softmax(q.k/sqrt32) @ v
// ---------------------------------------------------------------------------
__global__ __launch_bounds__(256) void attn_k(
    const float* __restrict__ q, const float* __restrict__ kl, const float* __restrict__ vl,
    float* __restrict__ out)
{
    __shared__ float k_lds[256][32];
    __shared__ float v_lds[256][32];
    const int t = threadIdx.x;
    const int h = blockIdx.y, b = blockIdx.z;
    const int n0 = blockIdx.x * 512;

    #pragma unroll
    for (int i = 0; i < 32; ++i) {
        int idx = t + i * 256; int dh = idx & 31, k = idx >> 5;
        size_t gi = ((size_t)b * K_ + k) * D_ + h * 32 + dh;
        k_lds[k][dh] = kl[gi];
        v_lds[k][dh] = vl[gi];
    }
    __syncthreads();

    const int n1 = n0 + t, n2 = n0 + 256 + t;
    const bool ok1 = n1 < N_, ok2 = n2 < N_;
    float4 q1[8], q2[8], o1[8], o2[8];
    const float4 z4 = {0.f, 0.f, 0.f, 0.f};
    const size_t qb1 = ((size_t)b * N_ + n1) * D_ + h * 32;
    const size_t qb2 = ((size_t)b * N_ + n2) * D_ + h * 32;
    #pragma unroll
    for (int i = 0; i < 8; ++i) {
        q1[i] = ok1 ? *(const float4*)&q[qb1 + i * 4] : z4;
        q2[i] = ok2 ? *(const float4*)&q[qb2 + i * 4] : z4;
        o1[i] = z4; o2[i] = z4;
    }
    float m1 = -3.4e38f, l1 = 0.f, m2 = -3.4e38f, l2 = 0.f;

    for (int k = 0; k < K_; ++k) {
        const float4* kr = (const float4*)k_lds[k];
        float s1 = 0.f, s2 = 0.f;
        #pragma unroll
        for (int i = 0; i < 8; ++i) {
            float4 kf = kr[i];
            s1 = fmaf(q1[i].x, kf.x, s1); s1 = fmaf(q1[i].y, kf.y, s1);
            s1 = fmaf(q1[i].z, kf.z, s1); s1 = fmaf(q1[i].w, kf.w, s1);
            s2 = fmaf(q2[i].x, kf.x, s2); s2 = fmaf(q2[i].y, kf.y, s2);
            s2 = fmaf(q2[i].z, kf.z, s2); s2 = fmaf(q2[i].w, kf.w, s2);
        }
        s1 *= 0.17677669529663687f; s2 *= 0.17677669529663687f;
        if (s1 > m1) {
            float sc = __expf(m1 - s1); l1 *= sc;
            #pragma unroll
            for (int i = 0; i < 8; ++i) { o1[i].x *= sc; o1[i].y *= sc; o1[i].z *= sc; o1[i].w *= sc; }
            m1 = s1;
        }
        if (s2 > m2) {
            float sc = __expf(m2 - s2); l2 *= sc;
            #pragma unroll
            for (int i = 0; i < 8; ++i) { o2[i].x *= sc; o2[i].y *= sc; o2[i].z *= sc; o2[i].w *= sc; }
            m2 = s2;
        }
        const float p1 = __expf(s1 - m1); l1 += p1;
        const float p2 = __expf(s2 - m2); l2 += p2;
        const float4* vr = (const float4*)v_lds[k];
        #pragma unroll
        for (int i = 0; i < 8; ++i) {
            float4 vf = vr[i];
            o1[i].x = fmaf(p1, vf.x, o1[i].x); o1[i].y = fmaf(p1, vf.y, o1[i].y);
            o1[i].z = fmaf(p1, vf.z, o1[i].z); o1[i].w = fmaf(p1, vf.w, o1[i].w);
            o2[i].x = fmaf(p2, vf.x, o2[i].x); o2[i].y = fmaf(p2, vf.y, o2[i].y);
            o2[i].z = fmaf(p2, vf.z, o2[i].z); o2[i].w = fmaf(p2, vf.w, o2[i].w);
        }
    }
    if (ok1) {
        const float inv = 1.f / l1;
        #pragma unroll
        for (int i = 0; i < 8; ++i) {
            float4 w = o1[i]; w.x *= inv; w.y *= inv; w.z *= inv; w.w *= inv;
            *(float4*)&out[qb1 + i * 4] = w;
        }
    }
    if (ok2) {
        const float inv = 1.f / l2;
        #pragma unroll
        for (int i = 0; i < 8; ++i) {
            float4 w = o2[i]; w.x *= inv; w.y *= inv; w.z *= inv; w.w *= inv;
            *(float4*)&out[qb2 + i * 4] = w;
        }
    }
}

// ---------------------------------------------------------------------------
// Row-sum over D: s_t[n*8 + b] = sum_d xe[b,n,d]   (transposed for fc reads)
// ---------------------------------------------------------------------------
__global__ __launch_bounds__(256) void rowsum_k(const float* __restrict__ xe, float* __restrict__ st)
{
    const int r = blockIdx.x * 4 + (threadIdx.x >> 6);
    const int lane = threadIdx.x & 63;
    const float2 v = *(const float2*)&xe[(size_t)r * D_ + 2 * lane];
    float sum = v.x + v.y;
    #pragma unroll
    for (int off = 32; off; off >>= 1) sum += __shfl_xor(sum, off);
    if (lane == 0) {
        const int b = r / N_, n = r % N_;
        st[(size_t)n * 8 + b] = sum;
    }
}

// ---------------------------------------------------------------------------
// Final FC + pool: out[b,m] = sum_n s[b,n]*fc_w[m,n] + 128*fc_b[m]
// 4 m-rows per block; fc_w read exactly once from HBM.
// ---------------------------------------------------------------------------
__global__ __launch_bounds__(256) void fc_k(
    const float* __restrict__ st, const float* __restrict__ fcw, const float* __restrict__ fcb,
    float* __restrict__ out)
{
    __shared__ float wred[4][4][8];
    const int t = threadIdx.x;
    const int m0 = blockIdx.x * 4;
    float acc[4][8] = {};
    for (int n = t; n < N_; n += 256) {
        const float4 sa = *(const float4*)&st[(size_t)n * 8];
        const float4 sb = *(const float4*)&st[(size_t)n * 8 + 4];
        #pragma unroll
        for (int mm = 0; mm < 4; ++mm) {
            const float w = fcw[(size_t)(m0 + mm) * N_ + n];
            acc[mm][0] = fmaf(w, sa.x, acc[mm][0]); acc[mm][1] = fmaf(w, sa.y, acc[mm][1]);
            acc[mm][2] = fmaf(w, sa.z, acc[mm][2]); acc[mm][3] = fmaf(w, sa.w, acc[mm][3]);
            acc[mm][4] = fmaf(w, sb.x, acc[mm][4]); acc[mm][5] = fmaf(w, sb.y, acc[mm][5]);
            acc[mm][6] = fmaf(w, sb.z, acc[mm][6]); acc[mm][7] = fmaf(w, sb.w, acc[mm][7]);
        }
    }
    #pragma unroll
    for (int mm = 0; mm < 4; ++mm)
        #pragma unroll
        for (int bb = 0; bb < 8; ++bb) {
            float v = acc[mm][bb];
            #pragma unroll
            for (int off = 32; off; off >>= 1) v += __shfl_xor(v, off);
            acc[mm][bb] = v;
        }
    const int lane = t & 63, w = t >> 6;
    if (lane == 0)
        #pragma unroll
        for (int mm = 0; mm < 4; ++mm)
            #pragma unroll
            for (int bb = 0; bb < 8; ++bb) wred[w][mm][bb] = acc[mm][bb];
    __syncthreads();
    if (t < 32) {
        const int mm = t >> 3, bb = t & 7;
        float v = wred[0][mm][bb] + wred[1][mm][bb] + wred[2][mm][bb] + wred[3][mm][bb];
        out[(size_t)bb * M_ + m0 + mm] = v + 128.f * fcb[m0 + mm];
    }
}

// ---------------------------------------------------------------------------
extern "C" void kernel_launch(void* const* d_in, const int* in_sizes, int n_in,
                              void* d_out, int out_size, void* d_ws, size_t ws_size,
                              hipStream_t stream)
{
    const float* x      = (const float*)d_in[0];
    const float* emb_w  = (const float*)d_in[1];
    const float* emb_b  = (const float*)d_in[2];
    const float* ln1_g  = (const float*)d_in[3];
    const float* ln1_b  = (const float*)d_in[4];
    const float* wq     = (const float*)d_in[5];
    const float* wk     = (const float*)d_in[6];
    const float* wv     = (const float*)d_in[7];
    const float* projk  = (const float*)d_in[8];
    const float* projv  = (const float*)d_in[9];
    const float* wo     = (const float*)d_in[10];
    const float* wo_b   = (const float*)d_in[11];
    const float* ln2_g  = (const float*)d_in[12];
    const float* ln2_b  = (const float*)d_in[13];
    const float* w1     = (const float*)d_in[14];
    const float* b1     = (const float*)d_in[15];
    const float* w2     = (const float*)d_in[16];
    const float* b2     = (const float*)d_in[17];
    const float* fcw    = (const float*)d_in[18];
    const float* fcb    = (const float*)d_in[19];
    float* out = (float*)d_out;

    // workspace layout (float offsets)
    const size_t BN   = (size_t)B_ * N_;            // 80000
    const size_t XE   = 0;                          // [B,N,D] fp32
    const size_t HN   = XE + BN * D_;               // [B,N,D] fp32 (hn / attn_out / hn2)
    const size_t QH   = HN + BN * D_;               // q fp32 [B,N,D] then hidden bf16 [B,N,512]
    const size_t LOWK = QH + BN * DFF_ / 2;         // [B,K,D] fp32
    const size_t LOWV = LOWK + (size_t)B_ * K_ * D_;
    const size_t KLOW = LOWV + (size_t)B_ * K_ * D_;
    const size_t VLOW = KLOW + (size_t)B_ * K_ * D_;
    const size_t ST   = VLOW + (size_t)B_ * K_ * D_; // s_t [N][B]
    float* wsf = (float*)d_ws;

    float* xe   = wsf + XE;
    float* hn   = wsf + HN;
    float* q    = wsf + QH;
    unsigned short* hid = (unsigned short*)(wsf + QH);
    float* lowK = wsf + LOWK;
    float* lowV = wsf + LOWV;
    float* klow = wsf + KLOW;
    float* vlow = wsf + VLOW;
    float* st   = wsf + ST;

    // zero the atomic-accumulated projection buffers (lowK, lowV contiguous)
    hipMemsetAsync(lowK, 0, (size_t)2 * B_ * K_ * D_ * sizeof(float), stream);

    // 1. embed + PE + LN1
    embed_ln_k<<<BN / 4, 256, 0, stream>>>(x, emb_w, emb_b, ln1_g, ln1_b, xe, hn);
    // 2. q = hn @ wq.T
    gemm_k<false, false, false, false, false><<<dim3(BN / 64, 1), 256, 0, stream>>>(hn, wq, nullptr, q, D_, D_);
    // 3. low-rank contractions over N (both proj_k and proj_v)
    proj_kernel<<<dim3(20, 8, 8), 256, 0, stream>>>(hn, projk, projv, lowK, lowV);
    // 4. k_low = lowK @ wk.T ; v_low = lowV @ wv.T
    gemm_k<false, false, false, false, false><<<dim3((size_t)B_ * K_ / 64, 1), 256, 0, stream>>>(lowK, wk, nullptr, klow, D_, D_);
    gemm_k<false, false, false, false, false><<<dim3((size_t)B_ * K_ / 64, 1), 256, 0, stream>>>(lowV, wv, nullptr, vlow, D_, D_);
    // 5. attention -> hn buffer (attn_out)
    attn_k<<<dim3(20, H_, B_), 256, 0, stream>>>(q, klow, vlow, hn);
    // 6. xe += attn_out @ wo.T + wo_b
    gemm_k<false, false, true, true, false><<<dim3(BN / 64, 1), 256, 0, stream>>>(hn, wo, wo_b, xe, D_, D_);
    // 7. hn2 = LN(xe; ln2)
    ln_k<<<BN / 4, 256, 0, stream>>>(xe, ln2_g, ln2_b, hn);
    // 8. hidden(bf16) = gelu(hn2 @ w1.T + b1)
    gemm_k<false, true, false, true, true><<<dim3(BN / 64, 4), 256, 0, stream>>>(hn, w1, b1, hid, DFF_, D_);
    // 9. xe += hidden @ w2.T + b2
    gemm_k<true, false, true, true, false><<<dim3(BN / 64, 1), 256, 0, stream>>>(hid, w2, b2, xe, D_, DFF_);
    // 10. s_t[n,b] = sum_d xe
    rowsum_k<<<BN / 4, 256, 0, stream>>>(xe, st);
    // 11. out[b,m] = s @ fc_w.T + 128*fc_b
    fc_k<<<M_ / 4, 256, 0, stream>>>(st, fcw, fcb, out);
}

// Round 2
// 566.160 us; speedup vs baseline: 2.4320x; 2.4320x over previous
//
#include <hip/hip_runtime.h>

constexpr int B_ = 8, N_ = 10000, D_ = 128, H_ = 4, K_ = 256, M_ = 5000, DFF_ = 512;
constexpr int NPAD = 10240;   // n padded to multiple of 32 for MFMA K-loop

typedef __attribute__((ext_vector_type(8))) short bf16x8;
typedef __attribute__((ext_vector_type(4))) float f32x4;

__device__ __forceinline__ float bf2f(unsigned short u) {
    unsigned x = ((unsigned)u) << 16; float f; __builtin_memcpy(&f, &x, 4); return f;
}
__device__ __forceinline__ unsigned short f2bf(float f) {
    unsigned x; __builtin_memcpy(&x, &f, 4);
    x = (x + 0x7fffu + ((x >> 16) & 1u)) >> 16;   // RNE
    return (unsigned short)x;
}
__device__ __forceinline__ unsigned pack2(float a, float b) {
    return (unsigned)f2bf(a) | ((unsigned)f2bf(b) << 16);
}
__device__ __forceinline__ float gelu_exact(float v) {
    return 0.5f * v * (1.0f + erff(v * 0.70710678118654752f));
}

// ---------------------------------------------------------------------------
// Weight f32 -> bf16 conversion (6 matrices)
// ---------------------------------------------------------------------------
__global__ __launch_bounds__(256) void cvt_w_k(
    const float* __restrict__ s0, const float* __restrict__ s1, const float* __restrict__ s2,
    const float* __restrict__ s3, const float* __restrict__ s4, const float* __restrict__ s5,
    unsigned short* __restrict__ d0, unsigned short* __restrict__ d1, unsigned short* __restrict__ d2,
    unsigned short* __restrict__ d3, unsigned short* __restrict__ d4, unsigned short* __restrict__ d5)
{
    const float* s; unsigned short* d; int sz;
    switch (blockIdx.y) {
        case 0: s = s0; d = d0; sz = 16384; break;
        case 1: s = s1; d = d1; sz = 16384; break;
        case 2: s = s2; d = d2; sz = 16384; break;
        case 3: s = s3; d = d3; sz = 16384; break;
        case 4: s = s4; d = d4; sz = 65536; break;
        default: s = s5; d = d5; sz = 65536; break;
    }
    const int idx = (blockIdx.x * 256 + threadIdx.x) * 8;
    if (idx >= sz) return;
    float4 a = *(const float4*)(s + idx);
    float4 b = *(const float4*)(s + idx + 4);
    uint4 p;
    p.x = pack2(a.x, a.y); p.y = pack2(a.z, a.w);
    p.z = pack2(b.x, b.y); p.w = pack2(b.z, b.w);
    *(uint4*)(d + idx) = p;
}

// ---------------------------------------------------------------------------
// Pt transpose: P[10000][256] f32 -> Pt[which][256][NPAD] bf16, zero-padded
// tile [64 n][128 k] via LDS, chunk-swizzled (chunk ^= n&15)
// ---------------------------------------------------------------------------
__global__ __launch_bounds__(256) void ptt_k(
    const float* __restrict__ pK, const float* __restrict__ pV, unsigned short* __restrict__ Pt)
{
    __shared__ __align__(16) char lds[16384];      // [64][128] bf16 swizzled
    const int t = threadIdx.x;
    const int n0 = blockIdx.x * 64, k0 = blockIdx.y * 128, which = blockIdx.z;
    const float* P = which ? pV : pK;
    {
        const int nl = t >> 2, cc = t & 3;
        const int n = n0 + nl;
        uint4 v[4] = {};
        if (n < N_) {
            const float4* src = (const float4*)(P + (size_t)n * K_ + k0 + cc * 32);
            #pragma unroll
            for (int j = 0; j < 4; ++j) {
                float4 a = src[2 * j], b = src[2 * j + 1];
                uint4 p; p.x = pack2(a.x, a.y); p.y = pack2(a.z, a.w);
                p.z = pack2(b.x, b.y); p.w = pack2(b.z, b.w);
                v[j] = p;
            }
        }
        #pragma unroll
        for (int j = 0; j < 4; ++j) {
            int ch = (cc * 4 + j) ^ (nl & 15);
            *(uint4*)(lds + nl * 256 + ch * 16) = v[j];
        }
    }
    __syncthreads();
    {
        const int eb = t >> 3, nb = t & 7;          // k0loc = eb*4, n' = nb*8
        unsigned short r0_[8], r1_[8], r2_[8], r3_[8];
        #pragma unroll
        for (int i = 0; i < 8; ++i) {
            int n = nb * 8 + i;
            int byte_ = n * 256 + (((eb >> 1) ^ (n & 15)) << 4) + ((eb & 1) << 3);
            uint2 dv = *(const uint2*)(lds + byte_);
            r0_[i] = (unsigned short)(dv.x & 0xffff); r1_[i] = (unsigned short)(dv.x >> 16);
            r2_[i] = (unsigned short)(dv.y & 0xffff); r3_[i] = (unsigned short)(dv.y >> 16);
        }
        size_t dbase = ((size_t)which * 256 + k0 + eb * 4) * NPAD + n0 + nb * 8;
        *(uint4*)&Pt[dbase]            = *(uint4*)r0_;
        *(uint4*)&Pt[dbase + NPAD]     = *(uint4*)r1_;
        *(uint4*)&Pt[dbase + 2 * NPAD] = *(uint4*)r2_;
        *(uint4*)&Pt[dbase + 3 * NPAD] = *(uint4*)r3_;
    }
}

// ---------------------------------------------------------------------------
// hnT transpose: hn[b*N+n][128] bf16 -> hnT[b][128][NPAD] bf16, zero-padded
// ---------------------------------------------------------------------------
__global__ __launch_bounds__(256) void hnt_k(
    const unsigned short* __restrict__ hn, unsigned short* __restrict__ hnT)
{
    __shared__ __align__(16) char lds[16384];
    const int t = threadIdx.x;
    const int n0 = blockIdx.x * 64, b = blockIdx.z;
    {
        const int nl = t >> 2, cc = t & 3;
        const int n = n0 + nl;
        uint4 v[4] = {};
        if (n < N_) {
            const uint4* src = (const uint4*)(hn + ((size_t)(b * N_ + n)) * D_ + cc * 32);
            #pragma unroll
            for (int j = 0; j < 4; ++j) v[j] = src[j];
        }
        #pragma unroll
        for (int j = 0; j < 4; ++j) {
            int ch = (cc * 4 + j) ^ (nl & 15);
            *(uint4*)(lds + nl * 256 + ch * 16) = v[j];
        }
    }
    __syncthreads();
    {
        const int eb = t >> 3, nb = t & 7;
        unsigned short r0_[8], r1_[8], r2_[8], r3_[8];
        #pragma unroll
        for (int i = 0; i < 8; ++i) {
            int n = nb * 8 + i;
            int byte_ = n * 256 + (((eb >> 1) ^ (n & 15)) << 4) + ((eb & 1) << 3);
            uint2 dv = *(const uint2*)(lds + byte_);
            r0_[i] = (unsigned short)(dv.x & 0xffff); r1_[i] = (unsigned short)(dv.x >> 16);
            r2_[i] = (unsigned short)(dv.y & 0xffff); r3_[i] = (unsigned short)(dv.y >> 16);
        }
        size_t dbase = ((size_t)b * 128 + eb * 4) * NPAD + n0 + nb * 8;
        *(uint4*)&hnT[dbase]            = *(uint4*)r0_;
        *(uint4*)&hnT[dbase + NPAD]     = *(uint4*)r1_;
        *(uint4*)&hnT[dbase + 2 * NPAD] = *(uint4*)r2_;
        *(uint4*)&hnT[dbase + 3 * NPAD] = *(uint4*)r3_;
    }
}

// ---------------------------------------------------------------------------
// embed + PE + LN1  (xe fp32, hn bf16)
// ---------------------------------------------------------------------------
__global__ __launch_bounds__(256) void embed_ln_k(
    const float* __restrict__ x, const float* __restrict__ ew, const float* __restrict__ eb,
    const float* __restrict__ g, const float* __restrict__ bb,
    float* __restrict__ xe, unsigned short* __restrict__ hnb)
{
    const int r = blockIdx.x * 4 + (threadIdx.x >> 6);
    const int lane = threadIdx.x & 63;
    const int n = r % N_;
    const float xv = x[r];
    const float ang = (float)n * expf((float)lane * -0.14391156829962788f);
    float sv, cv; sincosf(ang, &sv, &cv);
    const int d0 = 2 * lane;
    float e0 = xv * ew[d0]     + eb[d0]     + sv;
    float e1 = xv * ew[d0 + 1] + eb[d0 + 1] + cv;
    float sum = e0 + e1, sq = e0 * e0 + e1 * e1;
    #pragma unroll
    for (int off = 32; off; off >>= 1) { sum += __shfl_xor(sum, off); sq += __shfl_xor(sq, off); }
    const float mu = sum * (1.f / 128.f);
    const float var = sq * (1.f / 128.f) - mu * mu;
    const float rs = rsqrtf(var + 1e-5f);
    const size_t base = (size_t)r * D_ + d0;
    float2 ev; ev.x = e0; ev.y = e1;
    *(float2*)&xe[base] = ev;
    *(unsigned*)&hnb[base] = pack2((e0 - mu) * rs * g[d0] + bb[d0],
                                   (e1 - mu) * rs * g[d0 + 1] + bb[d0 + 1]);
}

// LN over D=128 -> bf16 out
__global__ __launch_bounds__(256) void ln_k(
    const float* __restrict__ in, const float* __restrict__ g, const float* __restrict__ bb,
    unsigned short* __restrict__ outb)
{
    const int r = blockIdx.x * 4 + (threadIdx.x >> 6);
    const int lane = threadIdx.x & 63;
    const int d0 = 2 * lane;
    const size_t base = (size_t)r * D_ + d0;
    const float2 ev = *(const float2*)&in[base];
    float sum = ev.x + ev.y, sq = ev.x * ev.x + ev.y * ev.y;
    #pragma unroll
    for (int off = 32; off; off >>= 1) { sum += __shfl_xor(sum, off); sq += __shfl_xor(sq, off); }
    const float mu = sum * (1.f / 128.f);
    const float var = sq * (1.f / 128.f) - mu * mu;
    const float rs = rsqrtf(var + 1e-5f);
    *(unsigned*)&outb[base] = pack2((ev.x - mu) * rs * g[d0] + bb[d0],
                                    (ev.y - mu) * rs * g[d0 + 1] + bb[d0 + 1]);
}

// ---------------------------------------------------------------------------
// MFMA GEMM: C[r,c] = sum_e A[r,e]*W[c,e]; A [M][E] bf16, W [NC][E] bf16.
// 128x128 tile, BK=32, 4 waves (2x2), each wave 4x4 frags of 16x16x32.
// LDS: A tile + W tile, 64B rows, 16B chunks swizzled by (row>>1)&3.
// ---------------------------------------------------------------------------
enum { M_Q = 0, M_PROJ = 1, M_SMALL = 2, M_WO = 3, M_W1 = 4, M_W2 = 5 };

template<int MODE>
__global__ __launch_bounds__(256) void mgemm_k(
    const unsigned short* __restrict__ Abase, const unsigned short* __restrict__ Wbase,
    const unsigned short* __restrict__ Walt,
    const float* __restrict__ bias, float* __restrict__ Cf, unsigned short* __restrict__ Cb)
{
    constexpr int NSTEP = (MODE == M_PROJ) ? 20 : (MODE == M_W2 ? 16 : 4);
    constexpr int SA = (MODE == M_PROJ) ? NPAD : (MODE == M_W2 ? 512 : 128);
    constexpr int SB = SA;
    constexpr int NCTOT = (MODE == M_W1) ? 512 : 128;
    constexpr bool HASBIAS = (MODE == M_WO || MODE == M_W1 || MODE == M_W2);
    constexpr bool GELU = (MODE == M_W1);
    constexpr bool RES = (MODE == M_WO || MODE == M_W2);
    constexpr bool OBF = (MODE == M_Q || MODE == M_W1);

    __shared__ __align__(16) char lds[16384];   // A: [0,8192), W: [8192,16384)

    const int t = threadIdx.x;
    const int bx = blockIdx.x, by = blockIdx.y, bz = blockIdx.z;

    const unsigned short* Ag; const unsigned short* Wg; size_t cbase;
    if (MODE == M_PROJ) {
        const int b = (bz >> 4) & 7, chunk = bz & 15, which = bz >> 7;
        Ag = Abase + (size_t)which * 256 * NPAD + (size_t)bx * 128 * NPAD + chunk * 640;
        Wg = Wbase + (size_t)b * 128 * NPAD + chunk * 640;
        cbase = (size_t)bz * 32768 + (size_t)bx * 16384;
    } else if (MODE == M_SMALL) {
        Ag = Abase + (size_t)bz * 2048 * 128 + (size_t)bx * 128 * 128;
        Wg = bz ? Walt : Wbase;
        cbase = (size_t)bz * 262144 + (size_t)bx * 16384;
    } else {
        Ag = Abase + (size_t)bx * 128 * SA;
        Wg = Wbase + (size_t)by * 128 * SB;
        cbase = (size_t)bx * 128 * NCTOT + (size_t)by * 128;
    }

    // staging: thread t stages row t>>1, 16B chunks {2(t&1), 2(t&1)+1} of A and W
    const int srow = t >> 1, hib = 2 * (t & 1);
    const unsigned short* aptr = Ag + (size_t)srow * SA + hib * 8;
    const unsigned short* wptr = Wg + (size_t)srow * SB + hib * 8;
    const int swz = (srow >> 1) & 3;
    char* la0 = lds + srow * 64 + ((hib ^ swz) << 4);
    char* la1 = lds + srow * 64 + (((hib + 1) ^ swz) << 4);
    char* lw0 = la0 + 8192;
    char* lw1 = la1 + 8192;

    // fragment read offsets (fixed across K-steps)
    const int w = t >> 6, l = t & 63;
    const int wrow = (w & 1) * 64, wcol = (w >> 1) * 64;
    int offA[4], offW[4];
    #pragma unroll
    for (int mi = 0; mi < 4; ++mi) {
        int ra = wrow + mi * 16 + (l & 15);
        offA[mi] = ra * 64 + (((l >> 4) ^ ((ra >> 1) & 3)) << 4);
        int rw = wcol + mi * 16 + (l & 15);
        offW[mi] = 8192 + rw * 64 + (((l >> 4) ^ ((rw >> 1) & 3)) << 4);
    }

    f32x4 acc[4][4] = {};

    for (int s = 0; s < NSTEP; ++s) {
        uint4 va0 = *(const uint4*)(aptr);
        uint4 va1 = *(const uint4*)(aptr + 8);
        uint4 vw0 = *(const uint4*)(wptr);
        uint4 vw1 = *(const uint4*)(wptr + 8);
        aptr += 32; wptr += 32;
        __syncthreads();
        *(uint4*)la0 = va0; *(uint4*)la1 = va1;
        *(uint4*)lw0 = vw0; *(uint4*)lw1 = vw1;
        __syncthreads();
        bf16x8 af[4], bf[4];
        #pragma unroll
        for (int mi = 0; mi < 4; ++mi) {
            af[mi] = *(const bf16x8*)(lds + offA[mi]);
            bf[mi] = *(const bf16x8*)(lds + offW[mi]);
        }
        #pragma unroll
        for (int mi = 0; mi < 4; ++mi)
            #pragma unroll
            for (int ni = 0; ni < 4; ++ni)
                acc[mi][ni] = __builtin_amdgcn_mfma_f32_16x16x32_bf16(af[mi], bf[ni], acc[mi][ni], 0, 0, 0);
    }

    // epilogue
    const int lrb = wrow + ((l >> 4) << 2);
    const int lcb = wcol + (l & 15);
    #pragma unroll
    for (int mi = 0; mi < 4; ++mi) {
        #pragma unroll
        for (int ni = 0; ni < 4; ++ni) {
            const int lc = lcb + ni * 16;
            #pragma unroll
            for (int r = 0; r < 4; ++r) {
                const int lr = lrb + mi * 16 + r;
                float v = acc[mi][ni][r];
                if (HASBIAS) v += bias[by * 128 + lc];
                if (GELU) v = gelu_exact(v);
                const size_t ci = cbase + (size_t)lr * NCTOT + lc;
                if (RES) v += Cf[ci];
                if (OBF) Cb[ci] = f2bf(v); else Cf[ci] = v;
            }
        }
    }
}

// ---------------------------------------------------------------------------
// reduce split-K partials -> lowKV bf16
// ---------------------------------------------------------------------------
__global__ __launch_bounds__(256) void reduce_k(
    const float* __restrict__ partials, unsigned short* __restrict__ lowKV)
{
    const int gid = blockIdx.x * 256 + threadIdx.x;          // < 524288
    const int wb = gid >> 15, r = gid & 32767;
    const float* p = partials + (size_t)wb * 16 * 32768 + r;
    float s = 0.f;
    #pragma unroll
    for (int c = 0; c < 16; ++c) s += p[c * 32768];
    lowKV[gid] = f2bf(s);
}

// ---------------------------------------------------------------------------
// Attention: q bf16, k/v fp32 (LDS), out bf16; online softmax, 2 rows/thread
// ---------------------------------------------------------------------------
__global__ __launch_bounds__(256) void attn_k(
    const unsigned short* __restrict__ q, const float* __restrict__ kl, const float* __restrict__ vl,
    unsigned short* __restrict__ outp)
{
    __shared__ float k_lds[256][32];
    __shared__ float v_lds[256][32];
    const int t = threadIdx.x;
    const int h = blockIdx.y, b = blockIdx.z;
    const int n0 = blockIdx.x * 512;

    #pragma unroll
    for (int i = 0; i < 32; ++i) {
        int idx = t + i * 256; int dh = idx & 31, k = idx >> 5;
        size_t gi = ((size_t)b * K_ + k) * D_ + h * 32 + dh;
        k_lds[k][dh] = kl[gi];
        v_lds[k][dh] = vl[gi];
    }
    __syncthreads();

    const int n1 = n0 + t, n2 = n0 + 256 + t;
    const bool ok1 = n1 < N_, ok2 = n2 < N_;
    const size_t qb1 = ((size_t)b * N_ + n1) * D_ + h * 32;
    const size_t qb2 = ((size_t)b * N_ + n2) * D_ + h * 32;
    float4 q1[8], q2[8], o1[8], o2[8];
    const uint4 z4u = {0, 0, 0, 0};
    #pragma unroll
    for (int i = 0; i < 4; ++i) {
        uint4 u1 = ok1 ? ((const uint4*)(q + qb1))[i] : z4u;
        uint4 u2 = ok2 ? ((const uint4*)(q + qb2))[i] : z4u;
        q1[2*i].x = bf2f(u1.x & 0xffff); q1[2*i].y = bf2f(u1.x >> 16);
        q1[2*i].z = bf2f(u1.y & 0xffff); q1[2*i].w = bf2f(u1.y >> 16);
        q1[2*i+1].x = bf2f(u1.z & 0xffff); q1[2*i+1].y = bf2f(u1.z >> 16);
        q1[2*i+1].z = bf2f(u1.w & 0xffff); q1[2*i+1].w = bf2f(u1.w >> 16);
        q2[2*i].x = bf2f(u2.x & 0xffff); q2[2*i].y = bf2f(u2.x >> 16);
        q2[2*i].z = bf2f(u2.y & 0xffff); q2[2*i].w = bf2f(u2.y >> 16);
        q2[2*i+1].x = bf2f(u2.z & 0xffff); q2[2*i+1].y = bf2f(u2.z >> 16);
        q2[2*i+1].z = bf2f(u2.w & 0xffff); q2[2*i+1].w = bf2f(u2.w >> 16);
    }
    #pragma unroll
    for (int i = 0; i < 8; ++i) { o1[i] = {0,0,0,0}; o2[i] = {0,0,0,0}; }
    float m1 = -3.4e38f, l1 = 0.f, m2 = -3.4e38f, l2 = 0.f;

    for (int k = 0; k < K_; ++k) {
        const float4* kr = (const float4*)k_lds[k];
        float s1 = 0.f, s2 = 0.f;
        #pragma unroll
        for (int i = 0; i < 8; ++i) {
            float4 kf = kr[i];
            s1 = fmaf(q1[i].x, kf.x, s1); s1 = fmaf(q1[i].y, kf.y, s1);
            s1 = fmaf(q1[i].z, kf.z, s1); s1 = fmaf(q1[i].w, kf.w, s1);
            s2 = fmaf(q2[i].x, kf.x, s2); s2 = fmaf(q2[i].y, kf.y, s2);
            s2 = fmaf(q2[i].z, kf.z, s2); s2 = fmaf(q2[i].w, kf.w, s2);
        }
        s1 *= 0.17677669529663687f; s2 *= 0.17677669529663687f;
        if (s1 > m1) {
            float sc = __expf(m1 - s1); l1 *= sc;
            #pragma unroll
            for (int i = 0; i < 8; ++i) { o1[i].x *= sc; o1[i].y *= sc; o1[i].z *= sc; o1[i].w *= sc; }
            m1 = s1;
        }
        if (s2 > m2) {
            float sc = __expf(m2 - s2); l2 *= sc;
            #pragma unroll
            for (int i = 0; i < 8; ++i) { o2[i].x *= sc; o2[i].y *= sc; o2[i].z *= sc; o2[i].w *= sc; }
            m2 = s2;
        }
        const float p1 = __expf(s1 - m1); l1 += p1;
        const float p2 = __expf(s2 - m2); l2 += p2;
        const float4* vr = (const float4*)v_lds[k];
        #pragma unroll
        for (int i = 0; i < 8; ++i) {
            float4 vf = vr[i];
            o1[i].x = fmaf(p1, vf.x, o1[i].x); o1[i].y = fmaf(p1, vf.y, o1[i].y);
            o1[i].z = fmaf(p1, vf.z, o1[i].z); o1[i].w = fmaf(p1, vf.w, o1[i].w);
            o2[i].x = fmaf(p2, vf.x, o2[i].x); o2[i].y = fmaf(p2, vf.y, o2[i].y);
            o2[i].z = fmaf(p2, vf.z, o2[i].z); o2[i].w = fmaf(p2, vf.w, o2[i].w);
        }
    }
    if (ok1) {
        const float inv = 1.f / l1;
        #pragma unroll
        for (int i = 0; i < 4; ++i) {
            uint4 u;
            u.x = pack2(o1[2*i].x * inv, o1[2*i].y * inv);
            u.y = pack2(o1[2*i].z * inv, o1[2*i].w * inv);
            u.z = pack2(o1[2*i+1].x * inv, o1[2*i+1].y * inv);
            u.w = pack2(o1[2*i+1].z * inv, o1[2*i+1].w * inv);
            ((uint4*)(outp + qb1))[i] = u;
        }
    }
    if (ok2) {
        const float inv = 1.f / l2;
        #pragma unroll
        for (int i = 0; i < 4; ++i) {
            uint4 u;
            u.x = pack2(o2[2*i].x * inv, o2[2*i].y * inv);
            u.y = pack2(o2[2*i].z * inv, o2[2*i].w * inv);
            u.z = pack2(o2[2*i+1].x * inv, o2[2*i+1].y * inv);
            u.w = pack2(o2[2*i+1].z * inv, o2[2*i+1].w * inv);
            ((uint4*)(outp + qb2))[i] = u;
        }
    }
}

// ---------------------------------------------------------------------------
// Row-sum over D -> s_t[n*8+b] ; final FC + pool
// ---------------------------------------------------------------------------
__global__ __launch_bounds__(256) void rowsum_k(const float* __restrict__ xe, float* __restrict__ st)
{
    const int r = blockIdx.x * 4 + (threadIdx.x >> 6);
    const int lane = threadIdx.x & 63;
    const float2 v = *(const float2*)&xe[(size_t)r * D_ + 2 * lane];
    float sum = v.x + v.y;
    #pragma unroll
    for (int off = 32; off; off >>= 1) sum += __shfl_xor(sum, off);
    if (lane == 0) {
        const int b = r / N_, n = r % N_;
        st[(size_t)n * 8 + b] = sum;
    }
}

__global__ __launch_bounds__(256) void fc_k(
    const float* __restrict__ st, const float* __restrict__ fcw, const float* __restrict__ fcb,
    float* __restrict__ out)
{
    __shared__ float wred[4][4][8];
    const int t = threadIdx.x;
    const int m0 = blockIdx.x * 4;
    float acc[4][8] = {};
    for (int n = t; n < N_; n += 256) {
        const float4 sa = *(const float4*)&st[(size_t)n * 8];
        const float4 sb = *(const float4*)&st[(size_t)n * 8 + 4];
        #pragma unroll
        for (int mm = 0; mm < 4; ++mm) {
            const float w = fcw[(size_t)(m0 + mm) * N_ + n];
            acc[mm][0] = fmaf(w, sa.x, acc[mm][0]); acc[mm][1] = fmaf(w, sa.y, acc[mm][1]);
            acc[mm][2] = fmaf(w, sa.z, acc[mm][2]); acc[mm][3] = fmaf(w, sa.w, acc[mm][3]);
            acc[mm][4] = fmaf(w, sb.x, acc[mm][4]); acc[mm][5] = fmaf(w, sb.y, acc[mm][5]);
            acc[mm][6] = fmaf(w, sb.z, acc[mm][6]); acc[mm][7] = fmaf(w, sb.w, acc[mm][7]);
        }
    }
    #pragma unroll
    for (int mm = 0; mm < 4; ++mm)
        #pragma unroll
        for (int bb = 0; bb < 8; ++bb) {
            float v = acc[mm][bb];
            #pragma unroll
            for (int off = 32; off; off >>= 1) v += __shfl_xor(v, off);
            acc[mm][bb] = v;
        }
    const int lane = t & 63, wv_ = t >> 6;
    if (lane == 0)
        #pragma unroll
        for (int mm = 0; mm < 4; ++mm)
            #pragma unroll
            for (int bb = 0; bb < 8; ++bb) wred[wv_][mm][bb] = acc[mm][bb];
    __syncthreads();
    if (t < 32) {
        const int mm = t >> 3, bb = t & 7;
        float v = wred[0][mm][bb] + wred[1][mm][bb] + wred[2][mm][bb] + wred[3][mm][bb];
        out[(size_t)bb * M_ + m0 + mm] = v + 128.f * fcb[m0 + mm];
    }
}

// ---------------------------------------------------------------------------
extern "C" void kernel_launch(void* const* d_in, const int* in_sizes, int n_in,
                              void* d_out, int out_size, void* d_ws, size_t ws_size,
                              hipStream_t stream)
{
    const float* x      = (const float*)d_in[0];
    const float* emb_w  = (const float*)d_in[1];
    const float* emb_b  = (const float*)d_in[2];
    const float* ln1_g  = (const float*)d_in[3];
    const float* ln1_b  = (const float*)d_in[4];
    const float* wq     = (const float*)d_in[5];
    const float* wk     = (const float*)d_in[6];
    const float* wv     = (const float*)d_in[7];
    const float* projk  = (const float*)d_in[8];
    const float* projv  = (const float*)d_in[9];
    const float* wo     = (const float*)d_in[10];
    const float* wo_b   = (const float*)d_in[11];
    const float* ln2_g  = (const float*)d_in[12];
    const float* ln2_b  = (const float*)d_in[13];
    const float* w1     = (const float*)d_in[14];
    const float* b1     = (const float*)d_in[15];
    const float* w2     = (const float*)d_in[16];
    const float* b2     = (const float*)d_in[17];
    const float* fcw    = (const float*)d_in[18];
    const float* fcb    = (const float*)d_in[19];
    float* out = (float*)d_out;

    // workspace layout (bytes)
    char* W = (char*)d_ws;
    float*          xe       = (float*)W;                              // 40,960,000
    unsigned short* hnb      = (unsigned short*)(W + 40960000);        // 20,480,000 (LN1 out / attn out / LN2 out)
    char*           region   = W + 61440000;
    unsigned short* qb       = (unsigned short*)region;                // 20,480,000
    unsigned short* hnT      = (unsigned short*)(region + 20480000);   // 20,971,520
    unsigned short* Pt       = (unsigned short*)(region + 41451520);   // 10,485,760
    float*          partials = (float*)(region + 51937280);            // 33,554,432
    unsigned short* hid      = (unsigned short*)region;                // 81,920,000 (aliases q/hnT/Pt/partials)
    unsigned short* lowKV    = (unsigned short*)(W + 146931712);       // 1,048,576
    float*          klow     = (float*)(W + 147980288);                // 2,097,152 (klow+vlow)
    float*          vlow     = klow + 262144;
    unsigned short* wqb      = (unsigned short*)(W + 150077440);
    unsigned short* wkb      = wqb + 16384;
    unsigned short* wvb      = wkb + 16384;
    unsigned short* wob      = wvb + 16384;
    unsigned short* w1b      = wob + 16384;
    unsigned short* w2b      = w1b + 65536;
    float*          st       = (float*)(W + 150470656);                // 320,000

    const size_t BN = (size_t)B_ * N_;

    cvt_w_k<<<dim3(32, 6), 256, 0, stream>>>(wq, wk, wv, wo, w1, w2, wqb, wkb, wvb, wob, w1b, w2b);
    ptt_k<<<dim3(160, 2, 2), 256, 0, stream>>>(projk, projv, Pt);
    embed_ln_k<<<BN / 4, 256, 0, stream>>>(x, emb_w, emb_b, ln1_g, ln1_b, xe, hnb);
    hnt_k<<<dim3(160, 1, 8), 256, 0, stream>>>(hnb, hnT);
    mgemm_k<M_Q><<<dim3(625, 1, 1), 256, 0, stream>>>(hnb, wqb, nullptr, nullptr, nullptr, qb);
    mgemm_k<M_PROJ><<<dim3(2, 1, 256), 256, 0, stream>>>(Pt, hnT, nullptr, nullptr, partials, nullptr);
    reduce_k<<<2048, 256, 0, stream>>>(partials, lowKV);
    mgemm_k<M_SMALL><<<dim3(16, 1, 2), 256, 0, stream>>>(lowKV, wkb, wvb, nullptr, klow, nullptr);
    attn_k<<<dim3(20, H_, B_), 256, 0, stream>>>(qb, klow, vlow, hnb);
    mgemm_k<M_WO><<<dim3(625, 1, 1), 256, 0, stream>>>(hnb, wob, nullptr, wo_b, xe, nullptr);
    ln_k<<<BN / 4, 256, 0, stream>>>(xe, ln2_g, ln2_b, hnb);
    mgemm_k<M_W1><<<dim3(625, 4, 1), 256, 0, stream>>>(hnb, w1b, nullptr, b1, nullptr, hid);
    mgemm_k<M_W2><<<dim3(625, 1, 1), 256, 0, stream>>>(hid, w2b, nullptr, b2, xe, nullptr);
    rowsum_k<<<BN / 4, 256, 0, stream>>>(xe, st);
    fc_k<<<M_ / 4, 256, 0, stream>>>(st, fcw, fcb, out);
}

// Round 4
// 344.140 us; speedup vs baseline: 4.0010x; 1.6451x over previous
//
#include <hip/hip_runtime.h>

constexpr int B_ = 8, N_ = 10000, D_ = 128, H_ = 4, K_ = 256, M_ = 5000, DFF_ = 512;
constexpr int NPAD = 10240;   // n padded to multiple of 32 for MFMA K-loop

typedef __attribute__((ext_vector_type(8))) short bf16x8;
typedef __attribute__((ext_vector_type(4))) float f32x4;

__device__ __forceinline__ float bf2f(unsigned short u) {
    unsigned x = ((unsigned)u) << 16; float f; __builtin_memcpy(&f, &x, 4); return f;
}
__device__ __forceinline__ unsigned short f2bf(float f) {
    unsigned x; __builtin_memcpy(&x, &f, 4);
    x = (x + 0x7fffu + ((x >> 16) & 1u)) >> 16;   // RNE
    return (unsigned short)x;
}
__device__ __forceinline__ unsigned pack2(float a, float b) {
    return (unsigned)f2bf(a) | ((unsigned)f2bf(b) << 16);
}
__device__ __forceinline__ float gelu_exact(float v) {
    return 0.5f * v * (1.0f + erff(v * 0.70710678118654752f));
}

// ---------------------------------------------------------------------------
// Weight f32 -> bf16 conversion (6 matrices)
// ---------------------------------------------------------------------------
__global__ __launch_bounds__(256) void cvt_w_k(
    const float* __restrict__ s0, const float* __restrict__ s1, const float* __restrict__ s2,
    const float* __restrict__ s3, const float* __restrict__ s4, const float* __restrict__ s5,
    unsigned short* __restrict__ d0, unsigned short* __restrict__ d1, unsigned short* __restrict__ d2,
    unsigned short* __restrict__ d3, unsigned short* __restrict__ d4, unsigned short* __restrict__ d5)
{
    const float* s; unsigned short* d; int sz;
    switch (blockIdx.y) {
        case 0: s = s0; d = d0; sz = 16384; break;
        case 1: s = s1; d = d1; sz = 16384; break;
        case 2: s = s2; d = d2; sz = 16384; break;
        case 3: s = s3; d = d3; sz = 16384; break;
        case 4: s = s4; d = d4; sz = 65536; break;
        default: s = s5; d = d5; sz = 65536; break;
    }
    const int idx = (blockIdx.x * 256 + threadIdx.x) * 8;
    if (idx >= sz) return;
    float4 a = *(const float4*)(s + idx);
    float4 b = *(const float4*)(s + idx + 4);
    uint4 p;
    p.x = pack2(a.x, a.y); p.y = pack2(a.z, a.w);
    p.z = pack2(b.x, b.y); p.w = pack2(b.z, b.w);
    *(uint4*)(d + idx) = p;
}

// ---------------------------------------------------------------------------
// Pt transpose: P[10000][256] f32 -> Pt[which][256][NPAD] bf16, zero-padded
// ---------------------------------------------------------------------------
__global__ __launch_bounds__(256) void ptt_k(
    const float* __restrict__ pK, const float* __restrict__ pV, unsigned short* __restrict__ Pt)
{
    __shared__ __align__(16) char lds[16384];      // [64][128] bf16 swizzled
    const int t = threadIdx.x;
    const int n0 = blockIdx.x * 64, k0 = blockIdx.y * 128, which = blockIdx.z;
    const float* P = which ? pV : pK;
    {
        const int nl = t >> 2, cc = t & 3;
        const int n = n0 + nl;
        uint4 v[4] = {};
        if (n < N_) {
            const float4* src = (const float4*)(P + (size_t)n * K_ + k0 + cc * 32);
            #pragma unroll
            for (int j = 0; j < 4; ++j) {
                float4 a = src[2 * j], b = src[2 * j + 1];
                uint4 p; p.x = pack2(a.x, a.y); p.y = pack2(a.z, a.w);
                p.z = pack2(b.x, b.y); p.w = pack2(b.z, b.w);
                v[j] = p;
            }
        }
        #pragma unroll
        for (int j = 0; j < 4; ++j) {
            int ch = (cc * 4 + j) ^ (nl & 15);
            *(uint4*)(lds + nl * 256 + ch * 16) = v[j];
        }
    }
    __syncthreads();
    {
        const int eb = t >> 3, nb = t & 7;
        unsigned short r0_[8], r1_[8], r2_[8], r3_[8];
        #pragma unroll
        for (int i = 0; i < 8; ++i) {
            int n = nb * 8 + i;
            int byte_ = n * 256 + (((eb >> 1) ^ (n & 15)) << 4) + ((eb & 1) << 3);
            uint2 dv = *(const uint2*)(lds + byte_);
            r0_[i] = (unsigned short)(dv.x & 0xffff); r1_[i] = (unsigned short)(dv.x >> 16);
            r2_[i] = (unsigned short)(dv.y & 0xffff); r3_[i] = (unsigned short)(dv.y >> 16);
        }
        size_t dbase = ((size_t)which * 256 + k0 + eb * 4) * NPAD + n0 + nb * 8;
        *(uint4*)&Pt[dbase]            = *(uint4*)r0_;
        *(uint4*)&Pt[dbase + NPAD]     = *(uint4*)r1_;
        *(uint4*)&Pt[dbase + 2 * NPAD] = *(uint4*)r2_;
        *(uint4*)&Pt[dbase + 3 * NPAD] = *(uint4*)r3_;
    }
}

// ---------------------------------------------------------------------------
// hnT transpose: hn[b*N+n][128] bf16 -> hnT[b][128][NPAD] bf16, zero-padded
// ---------------------------------------------------------------------------
__global__ __launch_bounds__(256) void hnt_k(
    const unsigned short* __restrict__ hn, unsigned short* __restrict__ hnT)
{
    __shared__ __align__(16) char lds[16384];
    const int t = threadIdx.x;
    const int n0 = blockIdx.x * 64, b = blockIdx.z;
    {
        const int nl = t >> 2, cc = t & 3;
        const int n = n0 + nl;
        uint4 v[4] = {};
        if (n < N_) {
            const uint4* src = (const uint4*)(hn + ((size_t)(b * N_ + n)) * D_ + cc * 32);
            #pragma unroll
            for (int j = 0; j < 4; ++j) v[j] = src[j];
        }
        #pragma unroll
        for (int j = 0; j < 4; ++j) {
            int ch = (cc * 4 + j) ^ (nl & 15);
            *(uint4*)(lds + nl * 256 + ch * 16) = v[j];
        }
    }
    __syncthreads();
    {
        const int eb = t >> 3, nb = t & 7;
        unsigned short r0_[8], r1_[8], r2_[8], r3_[8];
        #pragma unroll
        for (int i = 0; i < 8; ++i) {
            int n = nb * 8 + i;
            int byte_ = n * 256 + (((eb >> 1) ^ (n & 15)) << 4) + ((eb & 1) << 3);
            uint2 dv = *(const uint2*)(lds + byte_);
            r0_[i] = (unsigned short)(dv.x & 0xffff); r1_[i] = (unsigned short)(dv.x >> 16);
            r2_[i] = (unsigned short)(dv.y & 0xffff); r3_[i] = (unsigned short)(dv.y >> 16);
        }
        size_t dbase = ((size_t)b * 128 + eb * 4) * NPAD + n0 + nb * 8;
        *(uint4*)&hnT[dbase]            = *(uint4*)r0_;
        *(uint4*)&hnT[dbase + NPAD]     = *(uint4*)r1_;
        *(uint4*)&hnT[dbase + 2 * NPAD] = *(uint4*)r2_;
        *(uint4*)&hnT[dbase + 3 * NPAD] = *(uint4*)r3_;
    }
}

// ---------------------------------------------------------------------------
// embed + PE + LN1  (xe fp32, hn bf16)
// ---------------------------------------------------------------------------
__global__ __launch_bounds__(256) void embed_ln_k(
    const float* __restrict__ x, const float* __restrict__ ew, const float* __restrict__ eb,
    const float* __restrict__ g, const float* __restrict__ bb,
    float* __restrict__ xe, unsigned short* __restrict__ hnb)
{
    const int r = blockIdx.x * 4 + (threadIdx.x >> 6);
    const int lane = threadIdx.x & 63;
    const int n = r % N_;
    const float xv = x[r];
    const float ang = (float)n * expf((float)lane * -0.14391156829962788f);
    float sv, cv; sincosf(ang, &sv, &cv);
    const int d0 = 2 * lane;
    float e0 = xv * ew[d0]     + eb[d0]     + sv;
    float e1 = xv * ew[d0 + 1] + eb[d0 + 1] + cv;
    float sum = e0 + e1, sq = e0 * e0 + e1 * e1;
    #pragma unroll
    for (int off = 32; off; off >>= 1) { sum += __shfl_xor(sum, off); sq += __shfl_xor(sq, off); }
    const float mu = sum * (1.f / 128.f);
    const float var = sq * (1.f / 128.f) - mu * mu;
    const float rs = rsqrtf(var + 1e-5f);
    const size_t base = (size_t)r * D_ + d0;
    float2 ev; ev.x = e0; ev.y = e1;
    *(float2*)&xe[base] = ev;
    *(unsigned*)&hnb[base] = pack2((e0 - mu) * rs * g[d0] + bb[d0],
                                   (e1 - mu) * rs * g[d0 + 1] + bb[d0 + 1]);
}

// LN over D=128 -> bf16 out
__global__ __launch_bounds__(256) void ln_k(
    const float* __restrict__ in, const float* __restrict__ g, const float* __restrict__ bb,
    unsigned short* __restrict__ outb)
{
    const int r = blockIdx.x * 4 + (threadIdx.x >> 6);
    const int lane = threadIdx.x & 63;
    const int d0 = 2 * lane;
    const size_t base = (size_t)r * D_ + d0;
    const float2 ev = *(const float2*)&in[base];
    float sum = ev.x + ev.y, sq = ev.x * ev.x + ev.y * ev.y;
    #pragma unroll
    for (int off = 32; off; off >>= 1) { sum += __shfl_xor(sum, off); sq += __shfl_xor(sq, off); }
    const float mu = sum * (1.f / 128.f);
    const float var = sq * (1.f / 128.f) - mu * mu;
    const float rs = rsqrtf(var + 1e-5f);
    *(unsigned*)&outb[base] = pack2((ev.x - mu) * rs * g[d0] + bb[d0],
                                    (ev.y - mu) * rs * g[d0 + 1] + bb[d0 + 1]);
}

// ---------------------------------------------------------------------------
// MFMA GEMM (see R2). M_SMALL emits bf16.
// ---------------------------------------------------------------------------
enum { M_Q = 0, M_PROJ = 1, M_SMALL = 2, M_WO = 3, M_W1 = 4, M_W2 = 5 };

template<int MODE>
__global__ __launch_bounds__(256) void mgemm_k(
    const unsigned short* __restrict__ Abase, const unsigned short* __restrict__ Wbase,
    const unsigned short* __restrict__ Walt,
    const float* __restrict__ bias, float* __restrict__ Cf, unsigned short* __restrict__ Cb)
{
    constexpr int NSTEP = (MODE == M_PROJ) ? 20 : (MODE == M_W2 ? 16 : 4);
    constexpr int SA = (MODE == M_PROJ) ? NPAD : (MODE == M_W2 ? 512 : 128);
    constexpr int SB = SA;
    constexpr int NCTOT = (MODE == M_W1) ? 512 : 128;
    constexpr bool HASBIAS = (MODE == M_WO || MODE == M_W1 || MODE == M_W2);
    constexpr bool GELU = (MODE == M_W1);
    constexpr bool RES = (MODE == M_WO || MODE == M_W2);
    constexpr bool OBF = (MODE == M_Q || MODE == M_W1 || MODE == M_SMALL);

    __shared__ __align__(16) char lds[16384];

    const int t = threadIdx.x;
    const int bx = blockIdx.x, by = blockIdx.y, bz = blockIdx.z;

    const unsigned short* Ag; const unsigned short* Wg; size_t cbase;
    if (MODE == M_PROJ) {
        const int b = (bz >> 4) & 7, chunk = bz & 15, which = bz >> 7;
        Ag = Abase + (size_t)which * 256 * NPAD + (size_t)bx * 128 * NPAD + chunk * 640;
        Wg = Wbase + (size_t)b * 128 * NPAD + chunk * 640;
        cbase = (size_t)bz * 32768 + (size_t)bx * 16384;
    } else if (MODE == M_SMALL) {
        Ag = Abase + (size_t)bz * 2048 * 128 + (size_t)bx * 128 * 128;
        Wg = bz ? Walt : Wbase;
        cbase = (size_t)bz * 262144 + (size_t)bx * 16384;
    } else {
        Ag = Abase + (size_t)bx * 128 * SA;
        Wg = Wbase + (size_t)by * 128 * SB;
        cbase = (size_t)bx * 128 * NCTOT + (size_t)by * 128;
    }

    const int srow = t >> 1, hib = 2 * (t & 1);
    const unsigned short* aptr = Ag + (size_t)srow * SA + hib * 8;
    const unsigned short* wptr = Wg + (size_t)srow * SB + hib * 8;
    const int swz = (srow >> 1) & 3;
    char* la0 = lds + srow * 64 + ((hib ^ swz) << 4);
    char* la1 = lds + srow * 64 + (((hib + 1) ^ swz) << 4);
    char* lw0 = la0 + 8192;
    char* lw1 = la1 + 8192;

    const int w = t >> 6, l = t & 63;
    const int wrow = (w & 1) * 64, wcol = (w >> 1) * 64;
    int offA[4], offW[4];
    #pragma unroll
    for (int mi = 0; mi < 4; ++mi) {
        int ra = wrow + mi * 16 + (l & 15);
        offA[mi] = ra * 64 + (((l >> 4) ^ ((ra >> 1) & 3)) << 4);
        int rw = wcol + mi * 16 + (l & 15);
        offW[mi] = 8192 + rw * 64 + (((l >> 4) ^ ((rw >> 1) & 3)) << 4);
    }

    f32x4 acc[4][4] = {};

    for (int s = 0; s < NSTEP; ++s) {
        uint4 va0 = *(const uint4*)(aptr);
        uint4 va1 = *(const uint4*)(aptr + 8);
        uint4 vw0 = *(const uint4*)(wptr);
        uint4 vw1 = *(const uint4*)(wptr + 8);
        aptr += 32; wptr += 32;
        __syncthreads();
        *(uint4*)la0 = va0; *(uint4*)la1 = va1;
        *(uint4*)lw0 = vw0; *(uint4*)lw1 = vw1;
        __syncthreads();
        bf16x8 af[4], bfr[4];
        #pragma unroll
        for (int mi = 0; mi < 4; ++mi) {
            af[mi] = *(const bf16x8*)(lds + offA[mi]);
            bfr[mi] = *(const bf16x8*)(lds + offW[mi]);
        }
        #pragma unroll
        for (int mi = 0; mi < 4; ++mi)
            #pragma unroll
            for (int ni = 0; ni < 4; ++ni)
                acc[mi][ni] = __builtin_amdgcn_mfma_f32_16x16x32_bf16(af[mi], bfr[ni], acc[mi][ni], 0, 0, 0);
    }

    const int lrb = wrow + ((l >> 4) << 2);
    const int lcb = wcol + (l & 15);
    #pragma unroll
    for (int mi = 0; mi < 4; ++mi) {
        #pragma unroll
        for (int ni = 0; ni < 4; ++ni) {
            const int lc = lcb + ni * 16;
            #pragma unroll
            for (int r = 0; r < 4; ++r) {
                const int lr = lrb + mi * 16 + r;
                float v = acc[mi][ni][r];
                if (HASBIAS) v += bias[by * 128 + lc];
                if (GELU) v = gelu_exact(v);
                const size_t ci = cbase + (size_t)lr * NCTOT + lc;
                if (RES) v += Cf[ci];
                if (OBF) Cb[ci] = f2bf(v); else Cf[ci] = v;
            }
        }
    }
}

// ---------------------------------------------------------------------------
// reduce split-K partials -> lowKV bf16
// ---------------------------------------------------------------------------
__global__ __launch_bounds__(256) void reduce_k(
    const float* __restrict__ partials, unsigned short* __restrict__ lowKV)
{
    const int gid = blockIdx.x * 256 + threadIdx.x;
    const int wb = gid >> 15, r = gid & 32767;
    const float* p = partials + (size_t)wb * 16 * 32768 + r;
    float s = 0.f;
    #pragma unroll
    for (int c = 0; c < 16; ++c) s += p[c * 32768];
    lowKV[gid] = f2bf(s);
}

// ---------------------------------------------------------------------------
// MFMA attention. Per block: one (b,h), 256 q-rows, 4 waves x 64 q-rows.
// S^T = mfma(A=K, B=Q)  -> softmax over k in {regs x lane-groups}
// out^T = mfma(A=Vt, B=P^T), P staged [q][k] in per-wave LDS.
// K_lds swizzle is (r&3)<<4 — rows are 64B, a 3-bit XOR overflows the row
// (r7/r8 collide). Vt rows 512B use (r&7), P rows 128B use (r&7), out rows
// 64B use (r&3).
// ---------------------------------------------------------------------------
__global__ __launch_bounds__(256) void attn_mfma_k(
    const unsigned short* __restrict__ q, const unsigned short* __restrict__ kv,
    unsigned short* __restrict__ outp)
{
    __shared__ __align__(16) char lds[65536];
    const int t = threadIdx.x;
    const int w = t >> 6, l = t & 63;
    const int g = l >> 4, ql = l & 15;
    const int h = blockIdx.y, b = blockIdx.z;
    const int q0 = blockIdx.x * 256;
    const float SC = 0.17677669529663687f;   // 1/sqrt(32)

    // stage K_lds [256 rows][64 B]
    #pragma unroll
    for (int i = 0; i < 4; ++i) {
        const int r = (t >> 2) + 64 * i;
        const uint4 v = *(const uint4*)(kv + ((size_t)(b * 256 + r) * 128 + h * 32) + (t & 3) * 8);
        *(uint4*)(lds + r * 64 + (((t & 3) * 16) ^ ((r & 3) << 4))) = v;
    }
    // stage Vt_lds [32 rows][512 B] (transpose V on the fly, k-pairs packed)
    {
        const int kp = t & 127, dhalf = t >> 7;
        const unsigned short* vsrc = kv + 262144 + ((size_t)(b * 256 + 2 * kp) * 128 + h * 32 + 16 * dhalf);
        uint4 a0 = *(const uint4*)(vsrc);
        uint4 a1 = *(const uint4*)(vsrc + 8);
        uint4 c0 = *(const uint4*)(vsrc + 128);
        uint4 c1 = *(const uint4*)(vsrc + 136);
        const unsigned short* pa0 = (const unsigned short*)&a0;
        const unsigned short* pa1 = (const unsigned short*)&a1;
        const unsigned short* pc0 = (const unsigned short*)&c0;
        const unsigned short* pc1 = (const unsigned short*)&c1;
        #pragma unroll
        for (int j = 0; j < 8; ++j) {
            const int row = 16 * dhalf + j;
            unsigned u = (unsigned)pa0[j] | ((unsigned)pc0[j] << 16);
            *(unsigned*)(lds + 16384 + row * 512 + ((4 * kp) ^ ((row & 7) << 4))) = u;
        }
        #pragma unroll
        for (int j = 0; j < 8; ++j) {
            const int row = 16 * dhalf + 8 + j;
            unsigned u = (unsigned)pa1[j] | ((unsigned)pc1[j] << 16);
            *(unsigned*)(lds + 16384 + row * 512 + ((4 * kp) ^ ((row & 7) << 4))) = u;
        }
    }
    // Q fragments in registers (clamped rows)
    bf16x8 qfr[4];
    #pragma unroll
    for (int qf = 0; qf < 4; ++qf) {
        int n = q0 + w * 64 + qf * 16 + ql;
        if (n >= N_) n = N_ - 1;
        qfr[qf] = *(const bf16x8*)(q + ((size_t)(b * N_ + n) * 128 + h * 32 + g * 8));
    }
    __syncthreads();

    char* Pw = lds + 32768 + w * 8192;
    f32x4 oacc[2][4] = {};
    float m_run[4], l_run[4];
    #pragma unroll
    for (int qf = 0; qf < 4; ++qf) { m_run[qf] = -1e30f; l_run[qf] = 0.f; }

    for (int kt = 0; kt < 4; ++kt) {
        const int kb = kt * 64;
        bf16x8 kfr[4];
        #pragma unroll
        for (int kf = 0; kf < 4; ++kf) {
            const int r = kb + kf * 16 + ql;
            kfr[kf] = *(const bf16x8*)(lds + r * 64 + ((g * 16) ^ ((r & 3) << 4)));
        }
        f32x4 s_[4][4];
        #pragma unroll
        for (int kf = 0; kf < 4; ++kf)
            #pragma unroll
            for (int qf = 0; qf < 4; ++qf) {
                f32x4 z = {0.f, 0.f, 0.f, 0.f};
                s_[kf][qf] = __builtin_amdgcn_mfma_f32_16x16x32_bf16(kfr[kf], qfr[qf], z, 0, 0, 0);
            }
        #pragma unroll
        for (int qf = 0; qf < 4; ++qf) {
            float mx = -1e30f;
            #pragma unroll
            for (int kf = 0; kf < 4; ++kf)
                #pragma unroll
                for (int r = 0; r < 4; ++r) mx = fmaxf(mx, s_[kf][qf][r]);
            mx = fmaxf(mx, __shfl_xor(mx, 16));
            mx = fmaxf(mx, __shfl_xor(mx, 32));
            mx *= SC;
            const float mnew = fmaxf(m_run[qf], mx);
            const float corr = __expf(m_run[qf] - mnew);
            m_run[qf] = mnew;
            l_run[qf] *= corr;
            #pragma unroll
            for (int df = 0; df < 2; ++df) {
                oacc[df][qf][0] *= corr; oacc[df][qf][1] *= corr;
                oacc[df][qf][2] *= corr; oacc[df][qf][3] *= corr;
            }
            float p_[4][4]; float ssum = 0.f;
            #pragma unroll
            for (int kf = 0; kf < 4; ++kf)
                #pragma unroll
                for (int r = 0; r < 4; ++r) {
                    const float pv = __expf(s_[kf][qf][r] * SC - mnew);
                    p_[kf][r] = pv; ssum += pv;
                }
            ssum += __shfl_xor(ssum, 16);
            ssum += __shfl_xor(ssum, 32);
            l_run[qf] += ssum;
            const int qrow = qf * 16 + ql;
            #pragma unroll
            for (int kf = 0; kf < 4; ++kf) {
                uint2 pk;
                pk.x = pack2(p_[kf][0], p_[kf][1]);
                pk.y = pack2(p_[kf][2], p_[kf][3]);
                *(uint2*)(Pw + qrow * 128 + ((kf * 32 + g * 8) ^ ((qrow & 7) << 4))) = pk;
            }
        }
        asm volatile("s_waitcnt lgkmcnt(0)" ::: "memory");
        __builtin_amdgcn_sched_barrier(0);
        #pragma unroll
        for (int ks = 0; ks < 2; ++ks) {
            bf16x8 vt_[2];
            #pragma unroll
            for (int df = 0; df < 2; ++df) {
                const int row = df * 16 + ql;
                vt_[df] = *(const bf16x8*)(lds + 16384 + row * 512 +
                           ((kb * 2 + ks * 64 + g * 16) ^ ((row & 7) << 4)));
            }
            #pragma unroll
            for (int qf = 0; qf < 4; ++qf) {
                const int qrow = qf * 16 + ql;
                bf16x8 pf = *(const bf16x8*)(Pw + qrow * 128 + ((ks * 64 + g * 16) ^ ((qrow & 7) << 4)));
                #pragma unroll
                for (int df = 0; df < 2; ++df)
                    oacc[df][qf] = __builtin_amdgcn_mfma_f32_16x16x32_bf16(vt_[df], pf, oacc[df][qf], 0, 0, 0);
            }
        }
        asm volatile("s_waitcnt lgkmcnt(0)" ::: "memory");
        __builtin_amdgcn_sched_barrier(0);
    }

    // epilogue: normalize, transpose out^T -> [q][dh] via per-wave LDS, store
    float inv_[4];
    #pragma unroll
    for (int qf = 0; qf < 4; ++qf) inv_[qf] = 1.f / l_run[qf];
    #pragma unroll
    for (int qf = 0; qf < 4; ++qf) {
        const int qrow = qf * 16 + ql;
        #pragma unroll
        for (int df = 0; df < 2; ++df) {
            const unsigned lo = pack2(oacc[df][qf][0] * inv_[qf], oacc[df][qf][1] * inv_[qf]);
            const unsigned hi = pack2(oacc[df][qf][2] * inv_[qf], oacc[df][qf][3] * inv_[qf]);
            *(unsigned*)(Pw + qrow * 64 + ((df * 32 + g * 8) ^ ((qrow & 3) << 4))) = lo;
            *(unsigned*)(Pw + qrow * 64 + ((df * 32 + g * 8 + 4) ^ ((qrow & 3) << 4))) = hi;
        }
    }
    asm volatile("s_waitcnt lgkmcnt(0)" ::: "memory");
    __builtin_amdgcn_sched_barrier(0);
    #pragma unroll
    for (int pp = 0; pp < 4; ++pp) {
        const int qrow = pp * 16 + (l >> 2), c = l & 3;
        const uint4 v = *(const uint4*)(Pw + qrow * 64 + ((c * 16) ^ ((qrow & 3) << 4)));
        const int n = q0 + w * 64 + qrow;
        if (n < N_)
            *(uint4*)(outp + ((size_t)(b * N_ + n) * 128 + h * 32 + c * 8)) = v;
    }
}

// ---------------------------------------------------------------------------
// Row-sum over D -> s_t[n*8+b] ; final FC + pool
// ---------------------------------------------------------------------------
__global__ __launch_bounds__(256) void rowsum_k(const float* __restrict__ xe, float* __restrict__ st)
{
    const int r = blockIdx.x * 4 + (threadIdx.x >> 6);
    const int lane = threadIdx.x & 63;
    const float2 v = *(const float2*)&xe[(size_t)r * D_ + 2 * lane];
    float sum = v.x + v.y;
    #pragma unroll
    for (int off = 32; off; off >>= 1) sum += __shfl_xor(sum, off);
    if (lane == 0) {
        const int b = r / N_, n = r % N_;
        st[(size_t)n * 8 + b] = sum;
    }
}

__global__ __launch_bounds__(256) void fc_k(
    const float* __restrict__ st, const float* __restrict__ fcw, const float* __restrict__ fcb,
    float* __restrict__ out)
{
    __shared__ float wred[4][4][8];
    const int t = threadIdx.x;
    const int m0 = blockIdx.x * 4;
    float acc[4][8] = {};
    for (int n = t; n < N_; n += 256) {
        const float4 sa = *(const float4*)&st[(size_t)n * 8];
        const float4 sb = *(const float4*)&st[(size_t)n * 8 + 4];
        #pragma unroll
        for (int mm = 0; mm < 4; ++mm) {
            const float w = fcw[(size_t)(m0 + mm) * N_ + n];
            acc[mm][0] = fmaf(w, sa.x, acc[mm][0]); acc[mm][1] = fmaf(w, sa.y, acc[mm][1]);
            acc[mm][2] = fmaf(w, sa.z, acc[mm][2]); acc[mm][3] = fmaf(w, sa.w, acc[mm][3]);
            acc[mm][4] = fmaf(w, sb.x, acc[mm][4]); acc[mm][5] = fmaf(w, sb.y, acc[mm][5]);
            acc[mm][6] = fmaf(w, sb.z, acc[mm][6]); acc[mm][7] = fmaf(w, sb.w, acc[mm][7]);
        }
    }
    #pragma unroll
    for (int mm = 0; mm < 4; ++mm)
        #pragma unroll
        for (int bb = 0; bb < 8; ++bb) {
            float v = acc[mm][bb];
            #pragma unroll
            for (int off = 32; off; off >>= 1) v += __shfl_xor(v, off);
            acc[mm][bb] = v;
        }
    const int lane = t & 63, wv_ = t >> 6;
    if (lane == 0)
        #pragma unroll
        for (int mm = 0; mm < 4; ++mm)
            #pragma unroll
            for (int bb = 0; bb < 8; ++bb) wred[wv_][mm][bb] = acc[mm][bb];
    __syncthreads();
    if (t < 32) {
        const int mm = t >> 3, bb = t & 7;
        float v = wred[0][mm][bb] + wred[1][mm][bb] + wred[2][mm][bb] + wred[3][mm][bb];
        out[(size_t)bb * M_ + m0 + mm] = v + 128.f * fcb[m0 + mm];
    }
}

// ---------------------------------------------------------------------------
extern "C" void kernel_launch(void* const* d_in, const int* in_sizes, int n_in,
                              void* d_out, int out_size, void* d_ws, size_t ws_size,
                              hipStream_t stream)
{
    const float* x      = (const float*)d_in[0];
    const float* emb_w  = (const float*)d_in[1];
    const float* emb_b  = (const float*)d_in[2];
    const float* ln1_g  = (const float*)d_in[3];
    const float* ln1_b  = (const float*)d_in[4];
    const float* wq     = (const float*)d_in[5];
    const float* wk     = (const float*)d_in[6];
    const float* wv     = (const float*)d_in[7];
    const float* projk  = (const float*)d_in[8];
    const float* projv  = (const float*)d_in[9];
    const float* wo     = (const float*)d_in[10];
    const float* wo_b   = (const float*)d_in[11];
    const float* ln2_g  = (const float*)d_in[12];
    const float* ln2_b  = (const float*)d_in[13];
    const float* w1     = (const float*)d_in[14];
    const float* b1     = (const float*)d_in[15];
    const float* w2     = (const float*)d_in[16];
    const float* b2     = (const float*)d_in[17];
    const float* fcw    = (const float*)d_in[18];
    const float* fcb    = (const float*)d_in[19];
    float* out = (float*)d_out;

    char* W = (char*)d_ws;
    float*          xe       = (float*)W;
    unsigned short* hnb      = (unsigned short*)(W + 40960000);
    char*           region   = W + 61440000;
    unsigned short* qb       = (unsigned short*)region;
    unsigned short* hnT      = (unsigned short*)(region + 20480000);
    unsigned short* Pt       = (unsigned short*)(region + 41451520);
    float*          partials = (float*)(region + 51937280);
    unsigned short* hid      = (unsigned short*)region;
    unsigned short* lowKV    = (unsigned short*)(W + 146931712);
    unsigned short* klowb    = (unsigned short*)(W + 147980288);   // [2][2048][128] bf16
    unsigned short* wqb      = (unsigned short*)(W + 150077440);
    unsigned short* wkb      = wqb + 16384;
    unsigned short* wvb      = wkb + 16384;
    unsigned short* wob      = wvb + 16384;
    unsigned short* w1b      = wob + 16384;
    unsigned short* w2b      = w1b + 65536;
    float*          st       = (float*)(W + 150470656);

    const size_t BN = (size_t)B_ * N_;

    cvt_w_k<<<dim3(32, 6), 256, 0, stream>>>(wq, wk, wv, wo, w1, w2, wqb, wkb, wvb, wob, w1b, w2b);
    ptt_k<<<dim3(160, 2, 2), 256, 0, stream>>>(projk, projv, Pt);
    embed_ln_k<<<BN / 4, 256, 0, stream>>>(x, emb_w, emb_b, ln1_g, ln1_b, xe, hnb);
    hnt_k<<<dim3(160, 1, 8), 256, 0, stream>>>(hnb, hnT);
    mgemm_k<M_Q><<<dim3(625, 1, 1), 256, 0, stream>>>(hnb, wqb, nullptr, nullptr, nullptr, qb);
    mgemm_k<M_PROJ><<<dim3(2, 1, 256), 256, 0, stream>>>(Pt, hnT, nullptr, nullptr, partials, nullptr);
    reduce_k<<<2048, 256, 0, stream>>>(partials, lowKV);
    mgemm_k<M_SMALL><<<dim3(16, 1, 2), 256, 0, stream>>>(lowKV, wkb, wvb, nullptr, nullptr, klowb);
    attn_mfma_k<<<dim3(40, H_, B_), 256, 0, stream>>>(qb, klowb, hnb);
    mgemm_k<M_WO><<<dim3(625, 1, 1), 256, 0, stream>>>(hnb, wob, nullptr, wo_b, xe, nullptr);
    ln_k<<<BN / 4, 256, 0, stream>>>(xe, ln2_g, ln2_b, hnb);
    mgemm_k<M_W1><<<dim3(625, 4, 1), 256, 0, stream>>>(hnb, w1b, nullptr, b1, nullptr, hid);
    mgemm_k<M_W2><<<dim3(625, 1, 1), 256, 0, stream>>>(hid, w2b, nullptr, b2, xe, nullptr);
    rowsum_k<<<BN / 4, 256, 0, stream>>>(xe, st);
    fc_k<<<M_ / 4, 256, 0, stream>>>(st, fcw, fcb, out);
}

// Round 5
// 328.795 us; speedup vs baseline: 4.1878x; 1.0467x over previous
//
#include <hip/hip_runtime.h>

constexpr int B_ = 8, N_ = 10000, D_ = 128, H_ = 4, K_ = 256, M_ = 5000, DFF_ = 512;
constexpr int NPAD = 10240;   // n padded to multiple of 32 for MFMA K-loop

typedef __attribute__((ext_vector_type(8))) short bf16x8;
typedef __attribute__((ext_vector_type(4))) float f32x4;

__device__ __forceinline__ float bf2f(unsigned short u) {
    unsigned x = ((unsigned)u) << 16; float f; __builtin_memcpy(&f, &x, 4); return f;
}
__device__ __forceinline__ unsigned short f2bf(float f) {
    unsigned x; __builtin_memcpy(&x, &f, 4);
    x = (x + 0x7fffu + ((x >> 16) & 1u)) >> 16;   // RNE
    return (unsigned short)x;
}
__device__ __forceinline__ unsigned pack2(float a, float b) {
    return (unsigned)f2bf(a) | ((unsigned)f2bf(b) << 16);
}
__device__ __forceinline__ float gelu_exact(float v) {
    return 0.5f * v * (1.0f + erff(v * 0.70710678118654752f));
}

// ---------------------------------------------------------------------------
// Weight f32 -> bf16 conversion (6 matrices)
// ---------------------------------------------------------------------------
__global__ __launch_bounds__(256) void cvt_w_k(
    const float* __restrict__ s0, const float* __restrict__ s1, const float* __restrict__ s2,
    const float* __restrict__ s3, const float* __restrict__ s4, const float* __restrict__ s5,
    unsigned short* __restrict__ d0, unsigned short* __restrict__ d1, unsigned short* __restrict__ d2,
    unsigned short* __restrict__ d3, unsigned short* __restrict__ d4, unsigned short* __restrict__ d5)
{
    const float* s; unsigned short* d; int sz;
    switch (blockIdx.y) {
        case 0: s = s0; d = d0; sz = 16384; break;
        case 1: s = s1; d = d1; sz = 16384; break;
        case 2: s = s2; d = d2; sz = 16384; break;
        case 3: s = s3; d = d3; sz = 16384; break;
        case 4: s = s4; d = d4; sz = 65536; break;
        default: s = s5; d = d5; sz = 65536; break;
    }
    const int idx = (blockIdx.x * 256 + threadIdx.x) * 8;
    if (idx >= sz) return;
    float4 a = *(const float4*)(s + idx);
    float4 b = *(const float4*)(s + idx + 4);
    uint4 p;
    p.x = pack2(a.x, a.y); p.y = pack2(a.z, a.w);
    p.z = pack2(b.x, b.y); p.w = pack2(b.z, b.w);
    *(uint4*)(d + idx) = p;
}

// ---------------------------------------------------------------------------
// Pt transpose: P[10000][256] f32 -> Pt[which][256][NPAD] bf16, zero-padded
// ---------------------------------------------------------------------------
__global__ __launch_bounds__(256) void ptt_k(
    const float* __restrict__ pK, const float* __restrict__ pV, unsigned short* __restrict__ Pt)
{
    __shared__ __align__(16) char lds[16384];      // [64][128] bf16 swizzled
    const int t = threadIdx.x;
    const int n0 = blockIdx.x * 64, k0 = blockIdx.y * 128, which = blockIdx.z;
    const float* P = which ? pV : pK;
    {
        const int nl = t >> 2, cc = t & 3;
        const int n = n0 + nl;
        uint4 v[4] = {};
        if (n < N_) {
            const float4* src = (const float4*)(P + (size_t)n * K_ + k0 + cc * 32);
            #pragma unroll
            for (int j = 0; j < 4; ++j) {
                float4 a = src[2 * j], b = src[2 * j + 1];
                uint4 p; p.x = pack2(a.x, a.y); p.y = pack2(a.z, a.w);
                p.z = pack2(b.x, b.y); p.w = pack2(b.z, b.w);
                v[j] = p;
            }
        }
        #pragma unroll
        for (int j = 0; j < 4; ++j) {
            int ch = (cc * 4 + j) ^ (nl & 15);
            *(uint4*)(lds + nl * 256 + ch * 16) = v[j];
        }
    }
    __syncthreads();
    {
        const int eb = t >> 3, nb = t & 7;
        unsigned short r0_[8], r1_[8], r2_[8], r3_[8];
        #pragma unroll
        for (int i = 0; i < 8; ++i) {
            int n = nb * 8 + i;
            int byte_ = n * 256 + (((eb >> 1) ^ (n & 15)) << 4) + ((eb & 1) << 3);
            uint2 dv = *(const uint2*)(lds + byte_);
            r0_[i] = (unsigned short)(dv.x & 0xffff); r1_[i] = (unsigned short)(dv.x >> 16);
            r2_[i] = (unsigned short)(dv.y & 0xffff); r3_[i] = (unsigned short)(dv.y >> 16);
        }
        size_t dbase = ((size_t)which * 256 + k0 + eb * 4) * NPAD + n0 + nb * 8;
        *(uint4*)&Pt[dbase]            = *(uint4*)r0_;
        *(uint4*)&Pt[dbase + NPAD]     = *(uint4*)r1_;
        *(uint4*)&Pt[dbase + 2 * NPAD] = *(uint4*)r2_;
        *(uint4*)&Pt[dbase + 3 * NPAD] = *(uint4*)r3_;
    }
}

// ---------------------------------------------------------------------------
// hnT transpose: hn[b*N+n][128] bf16 -> hnT[b][128][NPAD] bf16, zero-padded
// ---------------------------------------------------------------------------
__global__ __launch_bounds__(256) void hnt_k(
    const unsigned short* __restrict__ hn, unsigned short* __restrict__ hnT)
{
    __shared__ __align__(16) char lds[16384];
    const int t = threadIdx.x;
    const int n0 = blockIdx.x * 64, b = blockIdx.z;
    {
        const int nl = t >> 2, cc = t & 3;
        const int n = n0 + nl;
        uint4 v[4] = {};
        if (n < N_) {
            const uint4* src = (const uint4*)(hn + ((size_t)(b * N_ + n)) * D_ + cc * 32);
            #pragma unroll
            for (int j = 0; j < 4; ++j) v[j] = src[j];
        }
        #pragma unroll
        for (int j = 0; j < 4; ++j) {
            int ch = (cc * 4 + j) ^ (nl & 15);
            *(uint4*)(lds + nl * 256 + ch * 16) = v[j];
        }
    }
    __syncthreads();
    {
        const int eb = t >> 3, nb = t & 7;
        unsigned short r0_[8], r1_[8], r2_[8], r3_[8];
        #pragma unroll
        for (int i = 0; i < 8; ++i) {
            int n = nb * 8 + i;
            int byte_ = n * 256 + (((eb >> 1) ^ (n & 15)) << 4) + ((eb & 1) << 3);
            uint2 dv = *(const uint2*)(lds + byte_);
            r0_[i] = (unsigned short)(dv.x & 0xffff); r1_[i] = (unsigned short)(dv.x >> 16);
            r2_[i] = (unsigned short)(dv.y & 0xffff); r3_[i] = (unsigned short)(dv.y >> 16);
        }
        size_t dbase = ((size_t)b * 128 + eb * 4) * NPAD + n0 + nb * 8;
        *(uint4*)&hnT[dbase]            = *(uint4*)r0_;
        *(uint4*)&hnT[dbase + NPAD]     = *(uint4*)r1_;
        *(uint4*)&hnT[dbase + 2 * NPAD] = *(uint4*)r2_;
        *(uint4*)&hnT[dbase + 3 * NPAD] = *(uint4*)r3_;
    }
}

// ---------------------------------------------------------------------------
// embed + PE + LN1  (xe bf16, hn bf16)
// ---------------------------------------------------------------------------
__global__ __launch_bounds__(256) void embed_ln_k(
    const float* __restrict__ x, const float* __restrict__ ew, const float* __restrict__ eb,
    const float* __restrict__ g, const float* __restrict__ bb,
    unsigned short* __restrict__ xeb, unsigned short* __restrict__ hnb)
{
    const int r = blockIdx.x * 4 + (threadIdx.x >> 6);
    const int lane = threadIdx.x & 63;
    const int n = r % N_;
    const float xv = x[r];
    const float ang = (float)n * expf((float)lane * -0.14391156829962788f);
    float sv, cv; sincosf(ang, &sv, &cv);
    const int d0 = 2 * lane;
    float e0 = xv * ew[d0]     + eb[d0]     + sv;
    float e1 = xv * ew[d0 + 1] + eb[d0 + 1] + cv;
    float sum = e0 + e1, sq = e0 * e0 + e1 * e1;
    #pragma unroll
    for (int off = 32; off; off >>= 1) { sum += __shfl_xor(sum, off); sq += __shfl_xor(sq, off); }
    const float mu = sum * (1.f / 128.f);
    const float var = sq * (1.f / 128.f) - mu * mu;
    const float rs = rsqrtf(var + 1e-5f);
    const size_t base = (size_t)r * D_ + d0;
    *(unsigned*)&xeb[base] = pack2(e0, e1);
    *(unsigned*)&hnb[base] = pack2((e0 - mu) * rs * g[d0] + bb[d0],
                                   (e1 - mu) * rs * g[d0 + 1] + bb[d0 + 1]);
}

// ---------------------------------------------------------------------------
// MFMA GEMM. Modes:
//  M_Q: q = hn@wq.T -> bf16
//  M_PROJ: split-K (8 chunks of 1280) Pt x hnT -> fp32 partials
//  M_SMALL: lowKV @ {wk,wv}.T -> bf16
//  M_WO: xe += attn@wo.T + wo_b, fused LN2 -> writes xeb(bf16) + hnb(bf16)
//  M_W1: gelu(hn2@w1.T + b1) -> bf16
//  M_W2: rowsum_d(xe + hid@w2.T + b2) -> st[n*8+b] only
// ---------------------------------------------------------------------------
enum { M_Q = 0, M_PROJ = 1, M_SMALL = 2, M_WO = 3, M_W1 = 4, M_W2 = 5 };

template<int MODE>
__global__ __launch_bounds__(256) void mgemm_k(
    const unsigned short* __restrict__ Abase, const unsigned short* __restrict__ Wbase,
    const unsigned short* __restrict__ Walt,
    const float* __restrict__ bias, float* __restrict__ Cf, unsigned short* __restrict__ Cb,
    const unsigned short* __restrict__ xebr, unsigned short* __restrict__ xebw,
    const float* __restrict__ lng, const float* __restrict__ lnb, float* __restrict__ st)
{
    constexpr int NSTEP = (MODE == M_PROJ) ? 40 : (MODE == M_W2 ? 16 : 4);
    constexpr int SA = (MODE == M_PROJ) ? NPAD : (MODE == M_W2 ? 512 : 128);
    constexpr int SB = SA;
    constexpr int NCTOT = (MODE == M_W1) ? 512 : 128;
    constexpr bool GELU = (MODE == M_W1);
    constexpr bool FUSED = (MODE == M_WO || MODE == M_W2);

    __shared__ __align__(16) char lds[16384];

    const int t = threadIdx.x;
    const int bx = blockIdx.x, by = blockIdx.y, bz = blockIdx.z;

    const unsigned short* Ag; const unsigned short* Wg; size_t cbase;
    if (MODE == M_PROJ) {
        const int b = (bz >> 3) & 7, chunk = bz & 7, which = bz >> 6;
        Ag = Abase + (size_t)which * 256 * NPAD + (size_t)bx * 128 * NPAD + chunk * 1280;
        Wg = Wbase + (size_t)b * 128 * NPAD + chunk * 1280;
        cbase = (size_t)bz * 32768 + (size_t)bx * 16384;
    } else if (MODE == M_SMALL) {
        Ag = Abase + (size_t)bz * 2048 * 128 + (size_t)bx * 128 * 128;
        Wg = bz ? Walt : Wbase;
        cbase = (size_t)bz * 262144 + (size_t)bx * 16384;
    } else {
        Ag = Abase + (size_t)bx * 128 * SA;
        Wg = Wbase + (size_t)by * 128 * SB;
        cbase = (size_t)bx * 128 * NCTOT + (size_t)by * 128;
    }

    const int srow = t >> 1, hib = 2 * (t & 1);
    const unsigned short* aptr = Ag + (size_t)srow * SA + hib * 8;
    const unsigned short* wptr = Wg + (size_t)srow * SB + hib * 8;
    const int swz = (srow >> 1) & 3;
    char* la0 = lds + srow * 64 + ((hib ^ swz) << 4);
    char* la1 = lds + srow * 64 + (((hib + 1) ^ swz) << 4);
    char* lw0 = la0 + 8192;
    char* lw1 = la1 + 8192;

    const int w = t >> 6, l = t & 63;
    const int g = l >> 4;
    const int wrow = (w & 1) * 64, wcol = (w >> 1) * 64;
    int offA[4], offW[4];
    #pragma unroll
    for (int mi = 0; mi < 4; ++mi) {
        int ra = wrow + mi * 16 + (l & 15);
        offA[mi] = ra * 64 + (((l >> 4) ^ ((ra >> 1) & 3)) << 4);
        int rw = wcol + mi * 16 + (l & 15);
        offW[mi] = 8192 + rw * 64 + (((l >> 4) ^ ((rw >> 1) & 3)) << 4);
    }

    f32x4 acc[4][4] = {};

    for (int s = 0; s < NSTEP; ++s) {
        uint4 va0 = *(const uint4*)(aptr);
        uint4 va1 = *(const uint4*)(aptr + 8);
        uint4 vw0 = *(const uint4*)(wptr);
        uint4 vw1 = *(const uint4*)(wptr + 8);
        aptr += 32; wptr += 32;
        __syncthreads();
        *(uint4*)la0 = va0; *(uint4*)la1 = va1;
        *(uint4*)lw0 = vw0; *(uint4*)lw1 = vw1;
        __syncthreads();
        bf16x8 af[4], bfr[4];
        #pragma unroll
        for (int mi = 0; mi < 4; ++mi) {
            af[mi] = *(const bf16x8*)(lds + offA[mi]);
            bfr[mi] = *(const bf16x8*)(lds + offW[mi]);
        }
        #pragma unroll
        for (int mi = 0; mi < 4; ++mi)
            #pragma unroll
            for (int ni = 0; ni < 4; ++ni)
                acc[mi][ni] = __builtin_amdgcn_mfma_f32_16x16x32_bf16(af[mi], bfr[ni], acc[mi][ni], 0, 0, 0);
    }

    const int lrb = wrow + (g << 2);
    const int lcb = wcol + (l & 15);

    if (FUSED) {
        // v = acc + bias + xeb residual; accumulate row sums (and sq for LN)
        float rsum[4][4], rsq[4][4];
        #pragma unroll
        for (int mi = 0; mi < 4; ++mi)
            #pragma unroll
            for (int r = 0; r < 4; ++r) { rsum[mi][r] = 0.f; rsq[mi][r] = 0.f; }
        #pragma unroll
        for (int mi = 0; mi < 4; ++mi)
            #pragma unroll
            for (int ni = 0; ni < 4; ++ni) {
                const int lc = lcb + ni * 16;
                #pragma unroll
                for (int r = 0; r < 4; ++r) {
                    const int lr = lrb + mi * 16 + r;
                    const size_t ci = cbase + (size_t)lr * 128 + lc;
                    float v = acc[mi][ni][r] + bias[lc] + bf2f(xebr[ci]);
                    acc[mi][ni][r] = v;
                    rsum[mi][r] += v;
                    if (MODE == M_WO) rsq[mi][r] += v * v;
                }
            }
        // reduce over the 16 col-lanes
        #pragma unroll
        for (int mi = 0; mi < 4; ++mi)
            #pragma unroll
            for (int r = 0; r < 4; ++r) {
                float s_ = rsum[mi][r], q_ = rsq[mi][r];
                #pragma unroll
                for (int off = 1; off < 16; off <<= 1) {
                    s_ += __shfl_xor(s_, off);
                    if (MODE == M_WO) q_ += __shfl_xor(q_, off);
                }
                rsum[mi][r] = s_; rsq[mi][r] = q_;
            }
        __syncthreads();                       // LDS tiles dead; reuse for cross-wave
        float2* red = (float2*)lds;            // [2][128]
        if ((l & 15) == 0) {
            #pragma unroll
            for (int mi = 0; mi < 4; ++mi)
                #pragma unroll
                for (int r = 0; r < 4; ++r) {
                    const int lr = lrb + mi * 16 + r;
                    float2 e; e.x = rsum[mi][r]; e.y = rsq[mi][r];
                    red[(w >> 1) * 128 + lr] = e;
                }
        }
        __syncthreads();
        if (MODE == M_WO) {
            #pragma unroll
            for (int mi = 0; mi < 4; ++mi)
                #pragma unroll
                for (int r = 0; r < 4; ++r) {
                    const int lr = lrb + mi * 16 + r;
                    const float2 e0 = red[lr], e1 = red[128 + lr];
                    const float mu = (e0.x + e1.x) * (1.f / 128.f);
                    const float var = (e0.y + e1.y) * (1.f / 128.f) - mu * mu;
                    const float rstd = rsqrtf(var + 1e-5f);
                    #pragma unroll
                    for (int ni = 0; ni < 4; ++ni) {
                        const int lc = lcb + ni * 16;
                        const size_t ci = cbase + (size_t)lr * 128 + lc;
                        const float xv = acc[mi][ni][r];
                        xebw[ci] = f2bf(xv);
                        Cb[ci] = f2bf((xv - mu) * rstd * lng[lc] + lnb[lc]);
                    }
                }
        } else {  // M_W2: store row sums only
            if ((l & 15) == 0 && (w >> 1) == 0) {
                #pragma unroll
                for (int mi = 0; mi < 4; ++mi)
                    #pragma unroll
                    for (int r = 0; r < 4; ++r) {
                        const int lr = lrb + mi * 16 + r;
                        const float total = red[lr].x + red[128 + lr].x;
                        const int grow = bx * 128 + lr;
                        const int bidx = grow / N_;
                        const int n = grow - bidx * N_;
                        st[(size_t)n * 8 + bidx] = total;
                    }
            }
        }
        return;
    }

    // generic epilogue (Q / PROJ / SMALL / W1)
    constexpr bool HASBIAS = (MODE == M_W1);
    constexpr bool OBF = (MODE == M_Q || MODE == M_W1 || MODE == M_SMALL);
    #pragma unroll
    for (int mi = 0; mi < 4; ++mi) {
        #pragma unroll
        for (int ni = 0; ni < 4; ++ni) {
            const int lc = lcb + ni * 16;
            #pragma unroll
            for (int r = 0; r < 4; ++r) {
                const int lr = lrb + mi * 16 + r;
                float v = acc[mi][ni][r];
                if (HASBIAS) v += bias[by * 128 + lc];
                if (GELU) v = gelu_exact(v);
                const size_t ci = cbase + (size_t)lr * NCTOT + lc;
                if (OBF) Cb[ci] = f2bf(v); else Cf[ci] = v;
            }
        }
    }
}

// ---------------------------------------------------------------------------
// reduce split-K partials (8 chunks) -> lowKV bf16
// ---------------------------------------------------------------------------
__global__ __launch_bounds__(256) void reduce_k(
    const float* __restrict__ partials, unsigned short* __restrict__ lowKV)
{
    const int gid = blockIdx.x * 256 + threadIdx.x;
    const int wb = gid >> 15, r = gid & 32767;
    const float* p = partials + (size_t)wb * 8 * 32768 + r;
    float s = 0.f;
    #pragma unroll
    for (int c = 0; c < 8; ++c) s += p[c * 32768];
    lowKV[gid] = f2bf(s);
}

// ---------------------------------------------------------------------------
// MFMA attention (see R4; K_lds swizzle (r&3)<<4 within 64B rows).
// ---------------------------------------------------------------------------
__global__ __launch_bounds__(256) void attn_mfma_k(
    const unsigned short* __restrict__ q, const unsigned short* __restrict__ kv,
    unsigned short* __restrict__ outp)
{
    __shared__ __align__(16) char lds[65536];
    const int t = threadIdx.x;
    const int w = t >> 6, l = t & 63;
    const int g = l >> 4, ql = l & 15;
    const int h = blockIdx.y, b = blockIdx.z;
    const int q0 = blockIdx.x * 256;
    const float SC = 0.17677669529663687f;   // 1/sqrt(32)

    #pragma unroll
    for (int i = 0; i < 4; ++i) {
        const int r = (t >> 2) + 64 * i;
        const uint4 v = *(const uint4*)(kv + ((size_t)(b * 256 + r) * 128 + h * 32) + (t & 3) * 8);
        *(uint4*)(lds + r * 64 + (((t & 3) * 16) ^ ((r & 3) << 4))) = v;
    }
    {
        const int kp = t & 127, dhalf = t >> 7;
        const unsigned short* vsrc = kv + 262144 + ((size_t)(b * 256 + 2 * kp) * 128 + h * 32 + 16 * dhalf);
        uint4 a0 = *(const uint4*)(vsrc);
        uint4 a1 = *(const uint4*)(vsrc + 8);
        uint4 c0 = *(const uint4*)(vsrc + 128);
        uint4 c1 = *(const uint4*)(vsrc + 136);
        const unsigned short* pa0 = (const unsigned short*)&a0;
        const unsigned short* pa1 = (const unsigned short*)&a1;
        const unsigned short* pc0 = (const unsigned short*)&c0;
        const unsigned short* pc1 = (const unsigned short*)&c1;
        #pragma unroll
        for (int j = 0; j < 8; ++j) {
            const int row = 16 * dhalf + j;
            unsigned u = (unsigned)pa0[j] | ((unsigned)pc0[j] << 16);
            *(unsigned*)(lds + 16384 + row * 512 + ((4 * kp) ^ ((row & 7) << 4))) = u;
        }
        #pragma unroll
        for (int j = 0; j < 8; ++j) {
            const int row = 16 * dhalf + 8 + j;
            unsigned u = (unsigned)pa1[j] | ((unsigned)pc1[j] << 16);
            *(unsigned*)(lds + 16384 + row * 512 + ((4 * kp) ^ ((row & 7) << 4))) = u;
        }
    }
    bf16x8 qfr[4];
    #pragma unroll
    for (int qf = 0; qf < 4; ++qf) {
        int n = q0 + w * 64 + qf * 16 + ql;
        if (n >= N_) n = N_ - 1;
        qfr[qf] = *(const bf16x8*)(q + ((size_t)(b * N_ + n) * 128 + h * 32 + g * 8));
    }
    __syncthreads();

    char* Pw = lds + 32768 + w * 8192;
    f32x4 oacc[2][4] = {};
    float m_run[4], l_run[4];
    #pragma unroll
    for (int qf = 0; qf < 4; ++qf) { m_run[qf] = -1e30f; l_run[qf] = 0.f; }

    for (int kt = 0; kt < 4; ++kt) {
        const int kb = kt * 64;
        bf16x8 kfr[4];
        #pragma unroll
        for (int kf = 0; kf < 4; ++kf) {
            const int r = kb + kf * 16 + ql;
            kfr[kf] = *(const bf16x8*)(lds + r * 64 + ((g * 16) ^ ((r & 3) << 4)));
        }
        f32x4 s_[4][4];
        #pragma unroll
        for (int kf = 0; kf < 4; ++kf)
            #pragma unroll
            for (int qf = 0; qf < 4; ++qf) {
                f32x4 z = {0.f, 0.f, 0.f, 0.f};
                s_[kf][qf] = __builtin_amdgcn_mfma_f32_16x16x32_bf16(kfr[kf], qfr[qf], z, 0, 0, 0);
            }
        #pragma unroll
        for (int qf = 0; qf < 4; ++qf) {
            float mx = -1e30f;
            #pragma unroll
            for (int kf = 0; kf < 4; ++kf)
                #pragma unroll
                for (int r = 0; r < 4; ++r) mx = fmaxf(mx, s_[kf][qf][r]);
            mx = fmaxf(mx, __shfl_xor(mx, 16));
            mx = fmaxf(mx, __shfl_xor(mx, 32));
            mx *= SC;
            if (mx > m_run[qf]) {
                const float corr = __expf(m_run[qf] - mx);
                l_run[qf] *= corr;
                #pragma unroll
                for (int df = 0; df < 2; ++df) {
                    oacc[df][qf][0] *= corr; oacc[df][qf][1] *= corr;
                    oacc[df][qf][2] *= corr; oacc[df][qf][3] *= corr;
                }
                m_run[qf] = mx;
            }
            float p_[4][4]; float ssum = 0.f;
            #pragma unroll
            for (int kf = 0; kf < 4; ++kf)
                #pragma unroll
                for (int r = 0; r < 4; ++r) {
                    const float pv = __expf(s_[kf][qf][r] * SC - m_run[qf]);
                    p_[kf][r] = pv; ssum += pv;
                }
            ssum += __shfl_xor(ssum, 16);
            ssum += __shfl_xor(ssum, 32);
            l_run[qf] += ssum;
            const int qrow = qf * 16 + ql;
            #pragma unroll
            for (int kf = 0; kf < 4; ++kf) {
                uint2 pk;
                pk.x = pack2(p_[kf][0], p_[kf][1]);
                pk.y = pack2(p_[kf][2], p_[kf][3]);
                *(uint2*)(Pw + qrow * 128 + ((kf * 32 + g * 8) ^ ((qrow & 7) << 4))) = pk;
            }
        }
        asm volatile("s_waitcnt lgkmcnt(0)" ::: "memory");
        __builtin_amdgcn_sched_barrier(0);
        #pragma unroll
        for (int ks = 0; ks < 2; ++ks) {
            bf16x8 vt_[2];
            #pragma unroll
            for (int df = 0; df < 2; ++df) {
                const int row = df * 16 + ql;
                vt_[df] = *(const bf16x8*)(lds + 16384 + row * 512 +
                           ((kb * 2 + ks * 64 + g * 16) ^ ((row & 7) << 4)));
            }
            #pragma unroll
            for (int qf = 0; qf < 4; ++qf) {
                const int qrow = qf * 16 + ql;
                bf16x8 pf = *(const bf16x8*)(Pw + qrow * 128 + ((ks * 64 + g * 16) ^ ((qrow & 7) << 4)));
                #pragma unroll
                for (int df = 0; df < 2; ++df)
                    oacc[df][qf] = __builtin_amdgcn_mfma_f32_16x16x32_bf16(vt_[df], pf, oacc[df][qf], 0, 0, 0);
            }
        }
        asm volatile("s_waitcnt lgkmcnt(0)" ::: "memory");
        __builtin_amdgcn_sched_barrier(0);
    }

    float inv_[4];
    #pragma unroll
    for (int qf = 0; qf < 4; ++qf) inv_[qf] = 1.f / l_run[qf];
    #pragma unroll
    for (int qf = 0; qf < 4; ++qf) {
        const int qrow = qf * 16 + ql;
        #pragma unroll
        for (int df = 0; df < 2; ++df) {
            const unsigned lo = pack2(oacc[df][qf][0] * inv_[qf], oacc[df][qf][1] * inv_[qf]);
            const unsigned hi = pack2(oacc[df][qf][2] * inv_[qf], oacc[df][qf][3] * inv_[qf]);
            *(unsigned*)(Pw + qrow * 64 + ((df * 32 + g * 8) ^ ((qrow & 3) << 4))) = lo;
            *(unsigned*)(Pw + qrow * 64 + ((df * 32 + g * 8 + 4) ^ ((qrow & 3) << 4))) = hi;
        }
    }
    asm volatile("s_waitcnt lgkmcnt(0)" ::: "memory");
    __builtin_amdgcn_sched_barrier(0);
    #pragma unroll
    for (int pp = 0; pp < 4; ++pp) {
        const int qrow = pp * 16 + (l >> 2), c = l & 3;
        const uint4 v = *(const uint4*)(Pw + qrow * 64 + ((c * 16) ^ ((qrow & 3) << 4)));
        const int n = q0 + w * 64 + qrow;
        if (n < N_)
            *(uint4*)(outp + ((size_t)(b * N_ + n) * 128 + h * 32 + c * 8)) = v;
    }
}

// ---------------------------------------------------------------------------
// Final FC + pool: out[b,m] = sum_n s[b,n]*fc_w[m,n] + 128*fc_b[m]
// ---------------------------------------------------------------------------
__global__ __launch_bounds__(256) void fc_k(
    const float* __restrict__ st, const float* __restrict__ fcw, const float* __restrict__ fcb,
    float* __restrict__ out)
{
    __shared__ float wred[4][4][8];
    const int t = threadIdx.x;
    const int m0 = blockIdx.x * 4;
    float acc[4][8] = {};
    for (int n = t; n < N_; n += 256) {
        const float4 sa = *(const float4*)&st[(size_t)n * 8];
        const float4 sb = *(const float4*)&st[(size_t)n * 8 + 4];
        #pragma unroll
        for (int mm = 0; mm < 4; ++mm) {
            const float w = fcw[(size_t)(m0 + mm) * N_ + n];
            acc[mm][0] = fmaf(w, sa.x, acc[mm][0]); acc[mm][1] = fmaf(w, sa.y, acc[mm][1]);
            acc[mm][2] = fmaf(w, sa.z, acc[mm][2]); acc[mm][3] = fmaf(w, sa.w, acc[mm][3]);
            acc[mm][4] = fmaf(w, sb.x, acc[mm][4]); acc[mm][5] = fmaf(w, sb.y, acc[mm][5]);
            acc[mm][6] = fmaf(w, sb.z, acc[mm][6]); acc[mm][7] = fmaf(w, sb.w, acc[mm][7]);
        }
    }
    #pragma unroll
    for (int mm = 0; mm < 4; ++mm)
        #pragma unroll
        for (int bb = 0; bb < 8; ++bb) {
            float v = acc[mm][bb];
            #pragma unroll
            for (int off = 32; off; off >>= 1) v += __shfl_xor(v, off);
            acc[mm][bb] = v;
        }
    const int lane = t & 63, wv_ = t >> 6;
    if (lane == 0)
        #pragma unroll
        for (int mm = 0; mm < 4; ++mm)
            #pragma unroll
            for (int bb = 0; bb < 8; ++bb) wred[wv_][mm][bb] = acc[mm][bb];
    __syncthreads();
    if (t < 32) {
        const int mm = t >> 3, bb = t & 7;
        float v = wred[0][mm][bb] + wred[1][mm][bb] + wred[2][mm][bb] + wred[3][mm][bb];
        out[(size_t)bb * M_ + m0 + mm] = v + 128.f * fcb[m0 + mm];
    }
}

// ---------------------------------------------------------------------------
extern "C" void kernel_launch(void* const* d_in, const int* in_sizes, int n_in,
                              void* d_out, int out_size, void* d_ws, size_t ws_size,
                              hipStream_t stream)
{
    const float* x      = (const float*)d_in[0];
    const float* emb_w  = (const float*)d_in[1];
    const float* emb_b  = (const float*)d_in[2];
    const float* ln1_g  = (const float*)d_in[3];
    const float* ln1_b  = (const float*)d_in[4];
    const float* wq     = (const float*)d_in[5];
    const float* wk     = (const float*)d_in[6];
    const float* wv     = (const float*)d_in[7];
    const float* projk  = (const float*)d_in[8];
    const float* projv  = (const float*)d_in[9];
    const float* wo     = (const float*)d_in[10];
    const float* wo_b   = (const float*)d_in[11];
    const float* ln2_g  = (const float*)d_in[12];
    const float* ln2_b  = (const float*)d_in[13];
    const float* w1     = (const float*)d_in[14];
    const float* b1     = (const float*)d_in[15];
    const float* w2     = (const float*)d_in[16];
    const float* b2     = (const float*)d_in[17];
    const float* fcw    = (const float*)d_in[18];
    const float* fcb    = (const float*)d_in[19];
    float* out = (float*)d_out;

    char* W = (char*)d_ws;
    unsigned short* xeb      = (unsigned short*)W;                     // 20,480,000
    unsigned short* hnb      = (unsigned short*)(W + 40960000);        // 20,480,000
    char*           region   = W + 61440000;
    unsigned short* qb       = (unsigned short*)region;                // 20,480,000
    unsigned short* hnT      = (unsigned short*)(region + 20480000);   // 20,971,520
    unsigned short* Pt       = (unsigned short*)(region + 41451520);   // 10,485,760
    float*          partials = (float*)(region + 51937280);            // 16,777,216 (8 chunks)
    unsigned short* hid      = (unsigned short*)region;                // 81,920,000 (aliases)
    unsigned short* lowKV    = (unsigned short*)(W + 146931712);
    unsigned short* klowb    = (unsigned short*)(W + 147980288);       // [2][2048][128] bf16
    unsigned short* wqb      = (unsigned short*)(W + 150077440);
    unsigned short* wkb      = wqb + 16384;
    unsigned short* wvb      = wkb + 16384;
    unsigned short* wob      = wvb + 16384;
    unsigned short* w1b      = wob + 16384;
    unsigned short* w2b      = w1b + 65536;
    float*          st       = (float*)(W + 150470656);

    const size_t BN = (size_t)B_ * N_;

    cvt_w_k<<<dim3(32, 6), 256, 0, stream>>>(wq, wk, wv, wo, w1, w2, wqb, wkb, wvb, wob, w1b, w2b);
    ptt_k<<<dim3(160, 2, 2), 256, 0, stream>>>(projk, projv, Pt);
    embed_ln_k<<<BN / 4, 256, 0, stream>>>(x, emb_w, emb_b, ln1_g, ln1_b, xeb, hnb);
    hnt_k<<<dim3(160, 1, 8), 256, 0, stream>>>(hnb, hnT);
    mgemm_k<M_Q><<<dim3(625, 1, 1), 256, 0, stream>>>(hnb, wqb, nullptr, nullptr, nullptr, qb,
                                                      nullptr, nullptr, nullptr, nullptr, nullptr);
    mgemm_k<M_PROJ><<<dim3(2, 1, 128), 256, 0, stream>>>(Pt, hnT, nullptr, nullptr, partials, nullptr,
                                                         nullptr, nullptr, nullptr, nullptr, nullptr);
    reduce_k<<<2048, 256, 0, stream>>>(partials, lowKV);
    mgemm_k<M_SMALL><<<dim3(16, 1, 2), 256, 0, stream>>>(lowKV, wkb, wvb, nullptr, nullptr, klowb,
                                                         nullptr, nullptr, nullptr, nullptr, nullptr);
    attn_mfma_k<<<dim3(40, H_, B_), 256, 0, stream>>>(qb, klowb, hnb);
    mgemm_k<M_WO><<<dim3(625, 1, 1), 256, 0, stream>>>(hnb, wob, nullptr, wo_b, nullptr, hnb,
                                                       xeb, xeb, ln2_g, ln2_b, nullptr);
    mgemm_k<M_W1><<<dim3(625, 4, 1), 256, 0, stream>>>(hnb, w1b, nullptr, b1, nullptr, hid,
                                                       nullptr, nullptr, nullptr, nullptr, nullptr);
    mgemm_k<M_W2><<<dim3(625, 1, 1), 256, 0, stream>>>(hid, w2b, nullptr, b2, nullptr, nullptr,
                                                       xeb, nullptr, nullptr, nullptr, st);
    fc_k<<<M_ / 4, 256, 0, stream>>>(st, fcw, fcb, out);
}